// Round 4
// baseline (479.718 us; speedup 1.0000x reference)
//
#include <hip/hip_runtime.h>
#include <hip/hip_bf16.h>

// Sizes fixed by the problem
#define BATCH 4
#define NSEQ  1024
#define DIM   768
#define NH    12
#define NKV   4
#define HD    64
#define NTOK  (BATCH*NSEQ)   // 4096

using bf16 = __hip_bfloat16;
typedef __attribute__((ext_vector_type(8))) short short8;
typedef __attribute__((ext_vector_type(4))) float floatx4;

__device__ __forceinline__ float b2f(short x) {
  unsigned u = ((unsigned)(unsigned short)x) << 16;
  return __builtin_bit_cast(float, u);
}
__device__ __forceinline__ unsigned short f2b(float f) {
  unsigned u = __builtin_bit_cast(unsigned, f);
  unsigned r = u + 0x7FFF + ((u >> 16) & 1);   // RNE
  return (unsigned short)(r >> 16);
}

// async global->LDS, 16B per lane; LDS dest = wave-uniform base + lane*16
__device__ __forceinline__ void load_lds_16(const bf16* g, bf16* l) {
  __builtin_amdgcn_global_load_lds(
      (const __attribute__((address_space(1))) void*)g,
      (__attribute__((address_space(3))) void*)l, 16, 0, 0);
}

// ---------------------------------------------------------------------------
// Fused f32->bf16 convert of all 6 input tensors (exact sizes hardcoded).
// ---------------------------------------------------------------------------
__global__ __launch_bounds__(256) void cvt_all(
    const float* __restrict__ x,  const float* __restrict__ wq,
    const float* __restrict__ wk, const float* __restrict__ wv1,
    const float* __restrict__ wv2, const float* __restrict__ wo,
    bf16* __restrict__ xb,  bf16* __restrict__ wqb, bf16* __restrict__ wkb,
    bf16* __restrict__ wv1b, bf16* __restrict__ wv2b, bf16* __restrict__ wob)
{
  int i = blockIdx.x * 256 + threadIdx.x;   // float4 index, total 1425408
  const float* s; bf16* d; int off;
  if      (i <  786432) { s = x;   d = xb;   off = i; }
  else if (i < 1081344) { s = wq;  d = wqb;  off = i -  786432; }
  else if (i < 1179648) { s = wk;  d = wkb;  off = i - 1081344; }
  else if (i < 1228800) { s = wv1; d = wv1b; off = i - 1179648; }
  else if (i < 1277952) { s = wv2; d = wv2b; off = i - 1228800; }
  else                  { s = wo;  d = wob;  off = i - 1277952; }
  float4 f = reinterpret_cast<const float4*>(s)[off];
  ushort4 u;
  u.x = f2b(f.x); u.y = f2b(f.y); u.z = f2b(f.z); u.w = f2b(f.w);
  reinterpret_cast<ushort4*>(d)[off] = u;
}

// ---------------------------------------------------------------------------
// Fused QKV projection GEMM, 128x128 tile, BK=32, global_load_lds staging.
// grid = (20 N-tiles, 32 M-tiles). N-tiles 0-11: q (rope+norm epilogue),
// 12-15: k (rope+norm), 16-17: v1, 18-19: v2 (plain).
// ---------------------------------------------------------------------------
__global__ __launch_bounds__(256, 2) void gemm_qkv(
    const bf16* __restrict__ xb,
    const bf16* __restrict__ Wqb, const bf16* __restrict__ Wkb,
    const bf16* __restrict__ Wv1b, const bf16* __restrict__ Wv2b,
    bf16* __restrict__ qb, bf16* __restrict__ kb,
    bf16* __restrict__ v1b, bf16* __restrict__ v2b)
{
  __shared__ __align__(16) bf16 As[128 * 32];
  __shared__ __align__(16) bf16 Ws[128 * 32];

  const int bn = blockIdx.x, bm = blockIdx.y;
  const bf16* Wp; bf16* Yp; int ldY; bool dorope;
  if (bn < 12)      { Wp = Wqb  + (size_t)bn * 128 * 768;        Yp = qb  + bn * 128;        ldY = 1536; dorope = true; }
  else if (bn < 16) { Wp = Wkb  + (size_t)(bn - 12) * 128 * 768; Yp = kb  + (bn - 12) * 128; ldY = 512;  dorope = true; }
  else if (bn < 18) { Wp = Wv1b + (size_t)(bn - 16) * 128 * 768; Yp = v1b + (bn - 16) * 128; ldY = 256;  dorope = false; }
  else              { Wp = Wv2b + (size_t)(bn - 18) * 128 * 768; Yp = v2b + (bn - 18) * 128; ldY = 256;  dorope = false; }

  const int t = threadIdx.x, wave = t >> 6, lane = t & 63;
  const int wm = wave >> 1, wn = wave & 1;
  const int quad = lane >> 4, lr = lane & 15;

  // staging: wave stages rows [wave*32, +32) of both tiles (2 chunks of 16 rows)
  const int srow = wave * 32 + (lane >> 2);
  const int scol = (lane & 3) * 8;
  const bf16* Ag = xb + (size_t)(bm * 128 + srow) * 768 + scol;
  const bf16* Wg = Wp + (size_t)srow * 768 + scol;
  bf16* Al0 = As + wave * 1024;          // chunk 2w   (1024 B)
  bf16* Al1 = As + wave * 1024 + 512;    // chunk 2w+1
  bf16* Wl0 = Ws + wave * 1024;
  bf16* Wl1 = Ws + wave * 1024 + 512;

  floatx4 acc[4][4] = {};

  for (int k0 = 0; k0 < 768; k0 += 32) {
    load_lds_16(Ag + k0,            Al0);
    load_lds_16(Ag + 16 * 768 + k0, Al1);
    load_lds_16(Wg + k0,            Wl0);
    load_lds_16(Wg + 16 * 768 + k0, Wl1);
    __syncthreads();

    short8 af[4], wf[4];
    #pragma unroll
    for (int mt = 0; mt < 4; ++mt)
      af[mt] = *reinterpret_cast<const short8*>(&As[(wm * 64 + mt * 16 + lr) * 32 + quad * 8]);
    #pragma unroll
    for (int nt = 0; nt < 4; ++nt)
      wf[nt] = *reinterpret_cast<const short8*>(&Ws[(wn * 64 + nt * 16 + lr) * 32 + quad * 8]);

    #pragma unroll
    for (int mt = 0; mt < 4; ++mt)
      #pragma unroll
      for (int nt = 0; nt < 4; ++nt)
        acc[mt][nt] = __builtin_amdgcn_mfma_f32_16x16x32_bf16(af[mt], wf[nt], acc[mt][nt], 0, 0, 0);
    __syncthreads();
  }

  // Epilogue. C/D: row = mt*16+quad*4+r (+wm*64), col = nt*16+lr (+wn*64)
  if (dorope) {
    // wave covers 64 consecutive cols = one full head. d = (nt*16+lr)&63... = nt*16+lr here? no:
    // col_local = wn*64 + nt*16 + lr; d = col_local & 63 = nt*16 + lr (since wn*64 ≡ 0 mod 64).
    const float K2 = 13.2877123795494f / 32.0f;   // log2(10000)/32
    float invf0 = exp2f(-(float)lr * K2);          // fi = lr        (nt even)
    float invf1 = exp2f(-(float)(16 + lr) * K2);   // fi = 16 + lr   (nt odd)
    #pragma unroll
    for (int mt = 0; mt < 4; ++mt) {
      #pragma unroll
      for (int r = 0; r < 4; ++r) {
        int row = bm * 128 + wm * 64 + mt * 16 + quad * 4 + r;
        int n = row & (NSEQ - 1);
        float ph = (float)(n >> 5), pw = (float)(n & 31);
        float roped[4]; float ss = 0.f;
        #pragma unroll
        for (int nt = 0; nt < 4; ++nt) {
          float v = acc[mt][nt][r];
          float partner = __shfl_xor(v, 1);
          float rot = (lr & 1) ? partner : -partner;   // d parity = lr parity
          float invf = (nt & 1) ? invf1 : invf0;
          float pos = (nt < 2) ? ph : pw;              // d<32 <=> nt<2
          float theta = pos * invf;
          float sn, cs;
          sincosf(theta, &sn, &cs);
          float rv = v * cs + rot * sn;
          roped[nt] = rv;
          ss += rv * rv;
        }
        #pragma unroll
        for (int off = 1; off < 16; off <<= 1) ss += __shfl_xor(ss, off);
        float sc = 1.f / (sqrtf(ss) + 1e-6f);
        #pragma unroll
        for (int nt = 0; nt < 4; ++nt) {
          int col = wn * 64 + nt * 16 + lr;
          *(unsigned short*)&Yp[(size_t)row * ldY + col] = f2b(roped[nt] * sc);
        }
      }
    }
  } else {
    #pragma unroll
    for (int mt = 0; mt < 4; ++mt)
      #pragma unroll
      for (int nt = 0; nt < 4; ++nt)
        #pragma unroll
        for (int r = 0; r < 4; ++r) {
          int row = bm * 128 + wm * 64 + mt * 16 + quad * 4 + r;
          int col = wn * 64 + nt * 16 + lr;
          *(unsigned short*)&Yp[(size_t)row * ldY + col] = f2b(acc[mt][nt][r]);
        }
  }
}

// ---------------------------------------------------------------------------
// Final GEMM: out = X @ Wo^T + bo, f32 out, 128x128 tile, global_load_lds.
// ---------------------------------------------------------------------------
__global__ __launch_bounds__(256, 2) void gemm_out(
    const bf16* __restrict__ Xb, const bf16* __restrict__ Wob,
    float* __restrict__ out, const float* __restrict__ bias)
{
  __shared__ __align__(16) bf16 As[128 * 32];
  __shared__ __align__(16) bf16 Ws[128 * 32];

  const int bn = blockIdx.x, bm = blockIdx.y;
  const int t = threadIdx.x, wave = t >> 6, lane = t & 63;
  const int wm = wave >> 1, wn = wave & 1;
  const int quad = lane >> 4, lr = lane & 15;

  const int srow = wave * 32 + (lane >> 2);
  const int scol = (lane & 3) * 8;
  const bf16* Ag = Xb  + (size_t)(bm * 128 + srow) * 768 + scol;
  const bf16* Wg = Wob + (size_t)(bn * 128 + srow) * 768 + scol;
  bf16* Al0 = As + wave * 1024;
  bf16* Al1 = As + wave * 1024 + 512;
  bf16* Wl0 = Ws + wave * 1024;
  bf16* Wl1 = Ws + wave * 1024 + 512;

  floatx4 acc[4][4] = {};

  for (int k0 = 0; k0 < 768; k0 += 32) {
    load_lds_16(Ag + k0,            Al0);
    load_lds_16(Ag + 16 * 768 + k0, Al1);
    load_lds_16(Wg + k0,            Wl0);
    load_lds_16(Wg + 16 * 768 + k0, Wl1);
    __syncthreads();

    short8 af[4], wf[4];
    #pragma unroll
    for (int mt = 0; mt < 4; ++mt)
      af[mt] = *reinterpret_cast<const short8*>(&As[(wm * 64 + mt * 16 + lr) * 32 + quad * 8]);
    #pragma unroll
    for (int nt = 0; nt < 4; ++nt)
      wf[nt] = *reinterpret_cast<const short8*>(&Ws[(wn * 64 + nt * 16 + lr) * 32 + quad * 8]);

    #pragma unroll
    for (int mt = 0; mt < 4; ++mt)
      #pragma unroll
      for (int nt = 0; nt < 4; ++nt)
        acc[mt][nt] = __builtin_amdgcn_mfma_f32_16x16x32_bf16(af[mt], wf[nt], acc[mt][nt], 0, 0, 0);
    __syncthreads();
  }

  #pragma unroll
  for (int nt = 0; nt < 4; ++nt) {
    int col = bn * 128 + wn * 64 + nt * 16 + lr;
    float bv = bias[col];
    #pragma unroll
    for (int mt = 0; mt < 4; ++mt)
      #pragma unroll
      for (int r = 0; r < 4; ++r) {
        int row = bm * 128 + wm * 64 + mt * 16 + quad * 4 + r;
        out[(size_t)row * 768 + col] = acc[mt][nt][r] + bv;
      }
  }
}

// ---------------------------------------------------------------------------
// V transpose (both streams in one launch):
// v[4096 tok][256] -> vt[b][kvh][64 d][1024 n]
// ---------------------------------------------------------------------------
__global__ __launch_bounds__(256) void transpose_v2(
    const bf16* __restrict__ v1, bf16* __restrict__ v1t,
    const bf16* __restrict__ v2, bf16* __restrict__ v2t)
{
  __shared__ bf16 tile[64][68];
  int blk = blockIdx.x;
  const bf16* v  = (blk >= 256) ? v2  : v1;
  bf16*       vt = (blk >= 256) ? v2t : v1t;
  blk &= 255;
  int ntile = blk & 15;
  int kvh = (blk >> 4) & 3;
  int b = blk >> 6;
  int t = threadIdx.x;
  int n0 = ntile * 64;

  #pragma unroll
  for (int l = 0; l < 4; ++l) {
    int nl = (t >> 4) + l * 16;
    int dl = (t & 15) * 4;
    ushort4 val = *reinterpret_cast<const ushort4*>(
        v + (size_t)(b * 1024 + n0 + nl) * 256 + kvh * 64 + dl);
    *reinterpret_cast<ushort4*>(&tile[nl][dl]) = val;
  }
  __syncthreads();
  #pragma unroll
  for (int l = 0; l < 4; ++l) {
    int dl = (t >> 4) + l * 16;
    int nl = (t & 15) * 4;
    ushort4 val;
    val.x = *(const unsigned short*)&tile[nl + 0][dl];
    val.y = *(const unsigned short*)&tile[nl + 1][dl];
    val.z = *(const unsigned short*)&tile[nl + 2][dl];
    val.w = *(const unsigned short*)&tile[nl + 3][dl];
    *reinterpret_cast<ushort4*>(
        vt + (size_t)((b * 4 + kvh) * 64 + dl) * 1024 + n0 + nl) = val;
  }
}

// ---------------------------------------------------------------------------
// MFMA flash attention, windowed, both streams + differential combine.
// Simplified softmax: scores bounded in [-1/8,1/8] (unit-norm q,k), so no
// running max / rescale; row sums accumulated in-lane, reduced once at end.
// Register prefetch of next K/V frags hides global latency.
// ---------------------------------------------------------------------------
__global__ __launch_bounds__(128, 3) void attn_mfma(
    const bf16* __restrict__ q, const bf16* __restrict__ k,
    const bf16* __restrict__ v1t, const bf16* __restrict__ v2t,
    const float* __restrict__ lambda_p, bf16* __restrict__ X)
{
  __shared__ __align__(16) char smem_raw[13440];

  const int bid = blockIdx.x;
  const int qh = bid & 31;
  const int hb = bid >> 5;          // h + 12*b
  const int h  = hb % 12;
  const int b  = hb / 12;
  const int kvh = h / 3;

  const int t = threadIdx.x;
  const int s = t >> 6;             // wave index = stream
  const int lane = t & 63;
  const int quad = lane >> 4, lr = lane & 15;

  bf16* Pl = (bf16*)smem_raw + s * 1280;   // [32][40] bf16 per wave

  const int tok0 = b * NSEQ + qh * 32;

  // Q fragments: A[m=lr (+16mt)][k=quad*8+j (+32ks)]
  short8 qf[2][2];
  #pragma unroll
  for (int mt = 0; mt < 2; ++mt)
    #pragma unroll
    for (int ks = 0; ks < 2; ++ks)
      qf[mt][ks] = *reinterpret_cast<const short8*>(
          q + (size_t)(tok0 + mt * 16 + lr) * 1536 + s * 768 + h * 64 + ks * 32 + quad * 8);

  // column mask addend (|qw - kw| > 8 -> -inf)
  float madd[2][2][4];
  #pragma unroll
  for (int mt = 0; mt < 2; ++mt)
    #pragma unroll
    for (int nt = 0; nt < 2; ++nt)
      #pragma unroll
      for (int r = 0; r < 4; ++r) {
        int qq = mt * 16 + quad * 4 + r;
        int km = nt * 16 + lr;
        int d = km - qq; if (d < 0) d = -d;
        madd[mt][nt][r] = (d <= 8) ? 0.f : -1e30f;
      }

  floatx4 O[2][4] = {};
  float psum[2][4] = {};

  const int kh0 = (qh > 8) ? qh - 8 : 0;
  const int kh1 = (qh < 23) ? qh + 8 : 31;
  const bf16* vbase = (s ? v2t : v1t) + (size_t)((b * 4 + kvh) * 64) * 1024;
  const int tkbase = b * NSEQ;

  short8 kf[2][2], vf[4];
  {
    const int tk0 = tkbase + kh0 * 32;
    #pragma unroll
    for (int nt = 0; nt < 2; ++nt)
      #pragma unroll
      for (int ks = 0; ks < 2; ++ks)
        kf[nt][ks] = *reinterpret_cast<const short8*>(
            k + (size_t)(tk0 + nt * 16 + lr) * 512 + s * 256 + kvh * 64 + ks * 32 + quad * 8);
    #pragma unroll
    for (int ntd = 0; ntd < 4; ++ntd)
      vf[ntd] = *reinterpret_cast<const short8*>(
          vbase + (size_t)(ntd * 16 + lr) * 1024 + kh0 * 32 + quad * 8);
  }

  for (int kh = kh0; kh <= kh1; ++kh) {
    // prefetch next K/V fragments (redundant reload of kh1 on last iter)
    short8 kf2[2][2], vf2[4];
    {
      const int khn = (kh < kh1) ? kh + 1 : kh1;
      const int tk0n = tkbase + khn * 32;
      #pragma unroll
      for (int nt = 0; nt < 2; ++nt)
        #pragma unroll
        for (int ks = 0; ks < 2; ++ks)
          kf2[nt][ks] = *reinterpret_cast<const short8*>(
              k + (size_t)(tk0n + nt * 16 + lr) * 512 + s * 256 + kvh * 64 + ks * 32 + quad * 8);
      #pragma unroll
      for (int ntd = 0; ntd < 4; ++ntd)
        vf2[ntd] = *reinterpret_cast<const short8*>(
            vbase + (size_t)(ntd * 16 + lr) * 1024 + khn * 32 + quad * 8);
    }

    // S = Q.K^T
    floatx4 S[2][2] = {};
    #pragma unroll
    for (int ks = 0; ks < 2; ++ks) {
      S[0][0] = __builtin_amdgcn_mfma_f32_16x16x32_bf16(qf[0][ks], kf[0][ks], S[0][0], 0, 0, 0);
      S[0][1] = __builtin_amdgcn_mfma_f32_16x16x32_bf16(qf[0][ks], kf[1][ks], S[0][1], 0, 0, 0);
      S[1][0] = __builtin_amdgcn_mfma_f32_16x16x32_bf16(qf[1][ks], kf[0][ks], S[1][0], 0, 0, 0);
      S[1][1] = __builtin_amdgcn_mfma_f32_16x16x32_bf16(qf[1][ks], kf[1][ks], S[1][1], 0, 0, 0);
    }

    // P = exp(S/8 + mask); accumulate row-sum partials; stage P to LDS
    #pragma unroll
    for (int mt = 0; mt < 2; ++mt)
      #pragma unroll
      for (int nt = 0; nt < 2; ++nt)
        #pragma unroll
        for (int r = 0; r < 4; ++r) {
          float p = __expf(fmaf(S[mt][nt][r], 0.125f, madd[mt][nt][r]));
          psum[mt][r] += p;
          *(unsigned short*)&Pl[(mt * 16 + quad * 4 + r) * 40 + nt * 16 + lr] = f2b(p);
        }

    // PV: A = P (from LDS), B = Vt frags
    short8 pf[2];
    #pragma unroll
    for (int mt = 0; mt < 2; ++mt)
      pf[mt] = *reinterpret_cast<const short8*>(&Pl[(mt * 16 + lr) * 40 + quad * 8]);

    #pragma unroll
    for (int mt = 0; mt < 2; ++mt)
      #pragma unroll
      for (int ntd = 0; ntd < 4; ++ntd)
        O[mt][ntd] = __builtin_amdgcn_mfma_f32_16x16x32_bf16(pf[mt], vf[ntd], O[mt][ntd], 0, 0, 0);

    #pragma unroll
    for (int nt = 0; nt < 2; ++nt)
      #pragma unroll
      for (int ks = 0; ks < 2; ++ks) kf[nt][ks] = kf2[nt][ks];
    #pragma unroll
    for (int ntd = 0; ntd < 4; ++ntd) vf[ntd] = vf2[ntd];
  }

  // one deferred row-sum reduction (rows lane-aligned with O)
  #pragma unroll
  for (int off = 1; off < 16; off <<= 1)
    #pragma unroll
    for (int mt = 0; mt < 2; ++mt)
      #pragma unroll
      for (int r = 0; r < 4; ++r)
        psum[mt][r] += __shfl_xor(psum[mt][r], off);

  #pragma unroll
  for (int mt = 0; mt < 2; ++mt)
    #pragma unroll
    for (int r = 0; r < 4; ++r)
      psum[mt][r] = 1.f / psum[mt][r];
  #pragma unroll
  for (int mt = 0; mt < 2; ++mt)
    #pragma unroll
    for (int ntd = 0; ntd < 4; ++ntd)
      #pragma unroll
      for (int r = 0; r < 4; ++r)
        O[mt][ntd][r] *= psum[mt][r];

  // combine: X = O1 - softplus(lambda)*O2
  float* Of = (float*)smem_raw;               // [32][68] f32
  bf16* Xs = (bf16*)(smem_raw + 8704);        // [32][72] bf16

  __syncthreads();
  if (s == 1) {
    #pragma unroll
    for (int mt = 0; mt < 2; ++mt)
      #pragma unroll
      for (int ntd = 0; ntd < 4; ++ntd)
        #pragma unroll
        for (int r = 0; r < 4; ++r)
          Of[(mt * 16 + quad * 4 + r) * 68 + ntd * 16 + lr] = O[mt][ntd][r];
  }
  __syncthreads();
  if (s == 0) {
    float lam = log1pf(__expf(lambda_p[h]));
    #pragma unroll
    for (int mt = 0; mt < 2; ++mt)
      #pragma unroll
      for (int ntd = 0; ntd < 4; ++ntd)
        #pragma unroll
        for (int r = 0; r < 4; ++r) {
          float o2 = Of[(mt * 16 + quad * 4 + r) * 68 + ntd * 16 + lr];
          float xv = O[mt][ntd][r] - lam * o2;
          *(unsigned short*)&Xs[(mt * 16 + quad * 4 + r) * 72 + ntd * 16 + lr] = f2b(xv);
        }
  }
  __syncthreads();

  #pragma unroll
  for (int slot = 0; slot < 2; ++slot) {
    int idx = slot * 128 + t;
    int row = idx >> 3, seg = idx & 7;
    short8 xv = *reinterpret_cast<const short8*>(&Xs[row * 72 + seg * 8]);
    *reinterpret_cast<short8*>(X + (size_t)(tok0 + row) * 768 + h * 64 + seg * 8) = xv;
  }
}

// ---------------------------------------------------------------------------
extern "C" void kernel_launch(void* const* d_in, const int* in_sizes, int n_in,
                              void* d_out, int out_size, void* d_ws, size_t ws_size,
                              hipStream_t stream)
{
  const float* x        = (const float*)d_in[0];
  const float* Wq       = (const float*)d_in[1];
  const float* Wk       = (const float*)d_in[2];
  const float* Wv1      = (const float*)d_in[3];
  const float* Wv2      = (const float*)d_in[4];
  const float* lambda_p = (const float*)d_in[5];
  const float* Wo       = (const float*)d_in[6];
  const float* bo       = (const float*)d_in[7];
  float* out = (float*)d_out;

  bf16* xb   = (bf16*)d_ws;                      // 4096*768
  bf16* Wqb  = xb   + (size_t)NTOK * 768;        // 1536*768
  bf16* Wkb  = Wqb  + (size_t)1536 * 768;        // 512*768
  bf16* Wv1b = Wkb  + (size_t)512 * 768;         // 256*768
  bf16* Wv2b = Wv1b + (size_t)256 * 768;         // 256*768
  bf16* Wob  = Wv2b + (size_t)256 * 768;         // 768*768
  bf16* qb   = Wob  + (size_t)768 * 768;         // 4096*1536
  bf16* kb   = qb   + (size_t)NTOK * 1536;       // 4096*512
  bf16* v1b  = kb   + (size_t)NTOK * 512;        // 4096*256
  bf16* v2b  = v1b  + (size_t)NTOK * 256;        // 4096*256
  bf16* Xb   = v2b  + (size_t)NTOK * 256;        // 4096*768
  bf16* v1t  = Xb   + (size_t)NTOK * 768;        // 4*4*64*1024
  bf16* v2t  = v1t  + (size_t)NTOK * 256;        // 4*4*64*1024

  cvt_all<<<5568, 256, 0, stream>>>(x, Wq, Wk, Wv1, Wv2, Wo,
                                    xb, Wqb, Wkb, Wv1b, Wv2b, Wob);

  gemm_qkv<<<dim3(20, 32), 256, 0, stream>>>(xb, Wqb, Wkb, Wv1b, Wv2b,
                                             qb, kb, v1b, v2b);

  transpose_v2<<<512, 256, 0, stream>>>(v1b, v1t, v2b, v2t);

  attn_mfma<<<BATCH * NH * 32, dim3(128), 0, stream>>>(qb, kb, v1t, v2t, lambda_p, Xb);

  gemm_out<<<dim3(6, 32), 256, 0, stream>>>(Xb, Wob, out, bo);
}

// Round 5
// 188.218 us; speedup vs baseline: 2.5487x; 2.5487x over previous
//
#include <hip/hip_runtime.h>
#include <hip/hip_bf16.h>

// Sizes fixed by the problem
#define BATCH 4
#define NSEQ  1024
#define DIM   768
#define NH    12
#define NKV   4
#define HD    64
#define NTOK  (BATCH*NSEQ)   // 4096

using bf16 = __hip_bfloat16;
typedef __attribute__((ext_vector_type(8))) short short8;
typedef __attribute__((ext_vector_type(4))) float floatx4;

__device__ __forceinline__ float b2f(short x) {
  unsigned u = ((unsigned)(unsigned short)x) << 16;
  return __builtin_bit_cast(float, u);
}
__device__ __forceinline__ unsigned short f2b(float f) {
  unsigned u = __builtin_bit_cast(unsigned, f);
  unsigned r = u + 0x7FFF + ((u >> 16) & 1);   // RNE
  return (unsigned short)(r >> 16);
}

// async global->LDS, 16B per lane; LDS dest = wave-uniform base + lane*16
__device__ __forceinline__ void load_lds_16(const bf16* g, bf16* l) {
  __builtin_amdgcn_global_load_lds(
      (const __attribute__((address_space(1))) void*)g,
      (__attribute__((address_space(3))) void*)l, 16, 0, 0);
}

// ---------------------------------------------------------------------------
// Fused f32->bf16 convert of all 6 input tensors (exact sizes hardcoded).
// ---------------------------------------------------------------------------
__global__ __launch_bounds__(256) void cvt_all(
    const float* __restrict__ x,  const float* __restrict__ wq,
    const float* __restrict__ wk, const float* __restrict__ wv1,
    const float* __restrict__ wv2, const float* __restrict__ wo,
    bf16* __restrict__ xb,  bf16* __restrict__ wqb, bf16* __restrict__ wkb,
    bf16* __restrict__ wv1b, bf16* __restrict__ wv2b, bf16* __restrict__ wob)
{
  int i = blockIdx.x * 256 + threadIdx.x;   // float4 index, total 1425408
  const float* s; bf16* d; int off;
  if      (i <  786432) { s = x;   d = xb;   off = i; }
  else if (i < 1081344) { s = wq;  d = wqb;  off = i -  786432; }
  else if (i < 1179648) { s = wk;  d = wkb;  off = i - 1081344; }
  else if (i < 1228800) { s = wv1; d = wv1b; off = i - 1179648; }
  else if (i < 1277952) { s = wv2; d = wv2b; off = i - 1228800; }
  else                  { s = wo;  d = wob;  off = i - 1277952; }
  float4 f = reinterpret_cast<const float4*>(s)[off];
  ushort4 u;
  u.x = f2b(f.x); u.y = f2b(f.y); u.z = f2b(f.z); u.w = f2b(f.w);
  reinterpret_cast<ushort4*>(d)[off] = u;
}

// ---------------------------------------------------------------------------
// Fused QKV projection GEMM, 128x128 tile, BK=32, global_load_lds staging.
// grid = (20 N-tiles, 32 M-tiles). N-tiles 0-11: q (rope+norm epilogue),
// 12-15: k (rope+norm), 16-17: v1, 18-19: v2 (plain).
// Epilogue rule: NO function calls with pointer args, NO array indexing
// inside call-bearing loops (sincosf demoted acc[][] to scratch in R4:
// 903 MB WRITE_SIZE, VGPR=52, MfmaUtil 2%). Only inline __sinf/__cosf.
// ---------------------------------------------------------------------------
__global__ __launch_bounds__(256, 2) void gemm_qkv(
    const bf16* __restrict__ xb,
    const bf16* __restrict__ Wqb, const bf16* __restrict__ Wkb,
    const bf16* __restrict__ Wv1b, const bf16* __restrict__ Wv2b,
    bf16* __restrict__ qb, bf16* __restrict__ kb,
    bf16* __restrict__ v1b, bf16* __restrict__ v2b)
{
  __shared__ __align__(16) bf16 As[128 * 32];
  __shared__ __align__(16) bf16 Ws[128 * 32];

  const int bn = blockIdx.x, bm = blockIdx.y;
  const bf16* Wp; bf16* Yp; int ldY; bool dorope;
  if (bn < 12)      { Wp = Wqb  + (size_t)bn * 128 * 768;        Yp = qb  + bn * 128;        ldY = 1536; dorope = true; }
  else if (bn < 16) { Wp = Wkb  + (size_t)(bn - 12) * 128 * 768; Yp = kb  + (bn - 12) * 128; ldY = 512;  dorope = true; }
  else if (bn < 18) { Wp = Wv1b + (size_t)(bn - 16) * 128 * 768; Yp = v1b + (bn - 16) * 128; ldY = 256;  dorope = false; }
  else              { Wp = Wv2b + (size_t)(bn - 18) * 128 * 768; Yp = v2b + (bn - 18) * 128; ldY = 256;  dorope = false; }

  const int t = threadIdx.x, wave = t >> 6, lane = t & 63;
  const int wm = wave >> 1, wn = wave & 1;
  const int quad = lane >> 4, lr = lane & 15;

  // staging: wave stages rows [wave*32, +32) of both tiles (2 chunks of 16 rows)
  const int srow = wave * 32 + (lane >> 2);
  const int scol = (lane & 3) * 8;
  const bf16* Ag = xb + (size_t)(bm * 128 + srow) * 768 + scol;
  const bf16* Wg = Wp + (size_t)srow * 768 + scol;
  bf16* Al0 = As + wave * 1024;          // chunk rows [w*32, w*32+16)
  bf16* Al1 = As + wave * 1024 + 512;    // chunk rows [w*32+16, w*32+32)
  bf16* Wl0 = Ws + wave * 1024;
  bf16* Wl1 = Ws + wave * 1024 + 512;

  floatx4 acc[4][4] = {};

  for (int k0 = 0; k0 < 768; k0 += 32) {
    load_lds_16(Ag + k0,            Al0);
    load_lds_16(Ag + 16 * 768 + k0, Al1);
    load_lds_16(Wg + k0,            Wl0);
    load_lds_16(Wg + 16 * 768 + k0, Wl1);
    __syncthreads();

    short8 af[4], wf[4];
    #pragma unroll
    for (int mt = 0; mt < 4; ++mt)
      af[mt] = *reinterpret_cast<const short8*>(&As[(wm * 64 + mt * 16 + lr) * 32 + quad * 8]);
    #pragma unroll
    for (int nt = 0; nt < 4; ++nt)
      wf[nt] = *reinterpret_cast<const short8*>(&Ws[(wn * 64 + nt * 16 + lr) * 32 + quad * 8]);

    #pragma unroll
    for (int mt = 0; mt < 4; ++mt)
      #pragma unroll
      for (int nt = 0; nt < 4; ++nt)
        acc[mt][nt] = __builtin_amdgcn_mfma_f32_16x16x32_bf16(af[mt], wf[nt], acc[mt][nt], 0, 0, 0);
    __syncthreads();
  }

  // Epilogue. C/D: row = wm*64 + mt*16 + quad*4 + r, col = wn*64 + nt*16 + lr
  if (dorope) {
    // head dim d = col & 63 = nt*16 + lr. fi = d%32, pos = (d<32 ? ph : pw).
    const float K2 = 0.41524101186098309f;         // log2(10000)/32
    const float invf0 = exp2f(-(float)lr * K2);    // nt even: fi = lr
    const float invf1 = exp2f(-(float)(16 + lr) * K2); // nt odd: fi = 16+lr
    const float sgn = (lr & 1) ? 1.f : -1.f;       // rot sign by d parity
    #pragma unroll
    for (int mt = 0; mt < 4; ++mt) {
      #pragma unroll
      for (int r = 0; r < 4; ++r) {
        int row = bm * 128 + wm * 64 + mt * 16 + quad * 4 + r;
        int n = row & (NSEQ - 1);
        float ph = (float)(n >> 5), pw = (float)(n & 31);
        // scalarize acc with constant indices BEFORE any transcendental
        float v0 = acc[mt][0][r];
        float v1 = acc[mt][1][r];
        float v2 = acc[mt][2][r];
        float v3 = acc[mt][3][r];
        float rot0 = sgn * __shfl_xor(v0, 1);   // partner element d^1
        float rot1 = sgn * __shfl_xor(v1, 1);
        float rot2 = sgn * __shfl_xor(v2, 1);
        float rot3 = sgn * __shfl_xor(v3, 1);
        float t0 = ph * invf0, t1 = ph * invf1, t2 = pw * invf0, t3 = pw * invf1;
        float rv0 = v0 * __cosf(t0) + rot0 * __sinf(t0);
        float rv1 = v1 * __cosf(t1) + rot1 * __sinf(t1);
        float rv2 = v2 * __cosf(t2) + rot2 * __sinf(t2);
        float rv3 = v3 * __cosf(t3) + rot3 * __sinf(t3);
        float ss = rv0 * rv0 + rv1 * rv1 + rv2 * rv2 + rv3 * rv3;
        #pragma unroll
        for (int off = 1; off < 16; off <<= 1) ss += __shfl_xor(ss, off);
        float sc = 1.f / (sqrtf(ss) + 1e-6f);
        size_t rbase = (size_t)row * ldY + wn * 64 + lr;
        *(unsigned short*)&Yp[rbase +  0] = f2b(rv0 * sc);
        *(unsigned short*)&Yp[rbase + 16] = f2b(rv1 * sc);
        *(unsigned short*)&Yp[rbase + 32] = f2b(rv2 * sc);
        *(unsigned short*)&Yp[rbase + 48] = f2b(rv3 * sc);
      }
    }
  } else {
    #pragma unroll
    for (int mt = 0; mt < 4; ++mt)
      #pragma unroll
      for (int nt = 0; nt < 4; ++nt)
        #pragma unroll
        for (int r = 0; r < 4; ++r) {
          int row = bm * 128 + wm * 64 + mt * 16 + quad * 4 + r;
          int col = wn * 64 + nt * 16 + lr;
          *(unsigned short*)&Yp[(size_t)row * ldY + col] = f2b(acc[mt][nt][r]);
        }
  }
}

// ---------------------------------------------------------------------------
// Final GEMM: out = X @ Wo^T + bo, f32 out, 128x128 tile, global_load_lds.
// ---------------------------------------------------------------------------
__global__ __launch_bounds__(256, 2) void gemm_out(
    const bf16* __restrict__ Xb, const bf16* __restrict__ Wob,
    float* __restrict__ out, const float* __restrict__ bias)
{
  __shared__ __align__(16) bf16 As[128 * 32];
  __shared__ __align__(16) bf16 Ws[128 * 32];

  const int bn = blockIdx.x, bm = blockIdx.y;
  const int t = threadIdx.x, wave = t >> 6, lane = t & 63;
  const int wm = wave >> 1, wn = wave & 1;
  const int quad = lane >> 4, lr = lane & 15;

  const int srow = wave * 32 + (lane >> 2);
  const int scol = (lane & 3) * 8;
  const bf16* Ag = Xb  + (size_t)(bm * 128 + srow) * 768 + scol;
  const bf16* Wg = Wob + (size_t)(bn * 128 + srow) * 768 + scol;
  bf16* Al0 = As + wave * 1024;
  bf16* Al1 = As + wave * 1024 + 512;
  bf16* Wl0 = Ws + wave * 1024;
  bf16* Wl1 = Ws + wave * 1024 + 512;

  floatx4 acc[4][4] = {};

  for (int k0 = 0; k0 < 768; k0 += 32) {
    load_lds_16(Ag + k0,            Al0);
    load_lds_16(Ag + 16 * 768 + k0, Al1);
    load_lds_16(Wg + k0,            Wl0);
    load_lds_16(Wg + 16 * 768 + k0, Wl1);
    __syncthreads();

    short8 af[4], wf[4];
    #pragma unroll
    for (int mt = 0; mt < 4; ++mt)
      af[mt] = *reinterpret_cast<const short8*>(&As[(wm * 64 + mt * 16 + lr) * 32 + quad * 8]);
    #pragma unroll
    for (int nt = 0; nt < 4; ++nt)
      wf[nt] = *reinterpret_cast<const short8*>(&Ws[(wn * 64 + nt * 16 + lr) * 32 + quad * 8]);

    #pragma unroll
    for (int mt = 0; mt < 4; ++mt)
      #pragma unroll
      for (int nt = 0; nt < 4; ++nt)
        acc[mt][nt] = __builtin_amdgcn_mfma_f32_16x16x32_bf16(af[mt], wf[nt], acc[mt][nt], 0, 0, 0);
    __syncthreads();
  }

  #pragma unroll
  for (int nt = 0; nt < 4; ++nt) {
    int col = bn * 128 + wn * 64 + nt * 16 + lr;
    float bv = bias[col];
    #pragma unroll
    for (int mt = 0; mt < 4; ++mt)
      #pragma unroll
      for (int r = 0; r < 4; ++r) {
        int row = bm * 128 + wm * 64 + mt * 16 + quad * 4 + r;
        out[(size_t)row * 768 + col] = acc[mt][nt][r] + bv;
      }
  }
}

// ---------------------------------------------------------------------------
// V transpose (both streams in one launch):
// v[4096 tok][256] -> vt[b][kvh][64 d][1024 n]
// ---------------------------------------------------------------------------
__global__ __launch_bounds__(256) void transpose_v2(
    const bf16* __restrict__ v1, bf16* __restrict__ v1t,
    const bf16* __restrict__ v2, bf16* __restrict__ v2t)
{
  __shared__ bf16 tile[64][68];
  int blk = blockIdx.x;
  const bf16* v  = (blk >= 256) ? v2  : v1;
  bf16*       vt = (blk >= 256) ? v2t : v1t;
  blk &= 255;
  int ntile = blk & 15;
  int kvh = (blk >> 4) & 3;
  int b = blk >> 6;
  int t = threadIdx.x;
  int n0 = ntile * 64;

  #pragma unroll
  for (int l = 0; l < 4; ++l) {
    int nl = (t >> 4) + l * 16;
    int dl = (t & 15) * 4;
    ushort4 val = *reinterpret_cast<const ushort4*>(
        v + (size_t)(b * 1024 + n0 + nl) * 256 + kvh * 64 + dl);
    *reinterpret_cast<ushort4*>(&tile[nl][dl]) = val;
  }
  __syncthreads();
  #pragma unroll
  for (int l = 0; l < 4; ++l) {
    int dl = (t >> 4) + l * 16;
    int nl = (t & 15) * 4;
    ushort4 val;
    val.x = *(const unsigned short*)&tile[nl + 0][dl];
    val.y = *(const unsigned short*)&tile[nl + 1][dl];
    val.z = *(const unsigned short*)&tile[nl + 2][dl];
    val.w = *(const unsigned short*)&tile[nl + 3][dl];
    *reinterpret_cast<ushort4*>(
        vt + (size_t)((b * 4 + kvh) * 64 + dl) * 1024 + n0 + nl) = val;
  }
}

// ---------------------------------------------------------------------------
// MFMA flash attention, windowed, both streams + differential combine.
// Unit-norm q,k -> scores in [-1/8,1/8]: no running max / rescale needed;
// row sums reduced once at end. Register prefetch of next K/V frags.
// ---------------------------------------------------------------------------
__global__ __launch_bounds__(128, 3) void attn_mfma(
    const bf16* __restrict__ q, const bf16* __restrict__ k,
    const bf16* __restrict__ v1t, const bf16* __restrict__ v2t,
    const float* __restrict__ lambda_p, bf16* __restrict__ X)
{
  __shared__ __align__(16) char smem_raw[13440];

  const int bid = blockIdx.x;
  const int qh = bid & 31;
  const int hb = bid >> 5;          // h + 12*b
  const int h  = hb % 12;
  const int b  = hb / 12;
  const int kvh = h / 3;

  const int t = threadIdx.x;
  const int s = t >> 6;             // wave index = stream
  const int lane = t & 63;
  const int quad = lane >> 4, lr = lane & 15;

  bf16* Pl = (bf16*)smem_raw + s * 1280;   // [32][40] bf16 per wave

  const int tok0 = b * NSEQ + qh * 32;

  // Q fragments: A[m=lr (+16mt)][k=quad*8+j (+32ks)]
  short8 qf[2][2];
  #pragma unroll
  for (int mt = 0; mt < 2; ++mt)
    #pragma unroll
    for (int ks = 0; ks < 2; ++ks)
      qf[mt][ks] = *reinterpret_cast<const short8*>(
          q + (size_t)(tok0 + mt * 16 + lr) * 1536 + s * 768 + h * 64 + ks * 32 + quad * 8);

  // column mask addend (|qw - kw| > 8 -> -inf)
  float madd[2][2][4];
  #pragma unroll
  for (int mt = 0; mt < 2; ++mt)
    #pragma unroll
    for (int nt = 0; nt < 2; ++nt)
      #pragma unroll
      for (int r = 0; r < 4; ++r) {
        int qq = mt * 16 + quad * 4 + r;
        int km = nt * 16 + lr;
        int d = km - qq; if (d < 0) d = -d;
        madd[mt][nt][r] = (d <= 8) ? 0.f : -1e30f;
      }

  floatx4 O[2][4] = {};
  float psum[2][4] = {};

  const int kh0 = (qh > 8) ? qh - 8 : 0;
  const int kh1 = (qh < 23) ? qh + 8 : 31;
  const bf16* vbase = (s ? v2t : v1t) + (size_t)((b * 4 + kvh) * 64) * 1024;
  const int tkbase = b * NSEQ;

  short8 kf[2][2], vf[4];
  {
    const int tk0 = tkbase + kh0 * 32;
    #pragma unroll
    for (int nt = 0; nt < 2; ++nt)
      #pragma unroll
      for (int ks = 0; ks < 2; ++ks)
        kf[nt][ks] = *reinterpret_cast<const short8*>(
            k + (size_t)(tk0 + nt * 16 + lr) * 512 + s * 256 + kvh * 64 + ks * 32 + quad * 8);
    #pragma unroll
    for (int ntd = 0; ntd < 4; ++ntd)
      vf[ntd] = *reinterpret_cast<const short8*>(
          vbase + (size_t)(ntd * 16 + lr) * 1024 + kh0 * 32 + quad * 8);
  }

  for (int kh = kh0; kh <= kh1; ++kh) {
    // prefetch next K/V fragments (redundant reload of kh1 on last iter)
    short8 kf2[2][2], vf2[4];
    {
      const int khn = (kh < kh1) ? kh + 1 : kh1;
      const int tk0n = tkbase + khn * 32;
      #pragma unroll
      for (int nt = 0; nt < 2; ++nt)
        #pragma unroll
        for (int ks = 0; ks < 2; ++ks)
          kf2[nt][ks] = *reinterpret_cast<const short8*>(
              k + (size_t)(tk0n + nt * 16 + lr) * 512 + s * 256 + kvh * 64 + ks * 32 + quad * 8);
      #pragma unroll
      for (int ntd = 0; ntd < 4; ++ntd)
        vf2[ntd] = *reinterpret_cast<const short8*>(
            vbase + (size_t)(ntd * 16 + lr) * 1024 + khn * 32 + quad * 8);
    }

    // S = Q.K^T
    floatx4 S[2][2] = {};
    #pragma unroll
    for (int ks = 0; ks < 2; ++ks) {
      S[0][0] = __builtin_amdgcn_mfma_f32_16x16x32_bf16(qf[0][ks], kf[0][ks], S[0][0], 0, 0, 0);
      S[0][1] = __builtin_amdgcn_mfma_f32_16x16x32_bf16(qf[0][ks], kf[1][ks], S[0][1], 0, 0, 0);
      S[1][0] = __builtin_amdgcn_mfma_f32_16x16x32_bf16(qf[1][ks], kf[0][ks], S[1][0], 0, 0, 0);
      S[1][1] = __builtin_amdgcn_mfma_f32_16x16x32_bf16(qf[1][ks], kf[1][ks], S[1][1], 0, 0, 0);
    }

    // P = exp(S/8 + mask); accumulate row-sum partials; stage P to LDS
    #pragma unroll
    for (int mt = 0; mt < 2; ++mt)
      #pragma unroll
      for (int nt = 0; nt < 2; ++nt)
        #pragma unroll
        for (int r = 0; r < 4; ++r) {
          float p = __expf(fmaf(S[mt][nt][r], 0.125f, madd[mt][nt][r]));
          psum[mt][r] += p;
          *(unsigned short*)&Pl[(mt * 16 + quad * 4 + r) * 40 + nt * 16 + lr] = f2b(p);
        }

    // PV: A = P (from LDS), B = Vt frags
    short8 pf[2];
    #pragma unroll
    for (int mt = 0; mt < 2; ++mt)
      pf[mt] = *reinterpret_cast<const short8*>(&Pl[(mt * 16 + lr) * 40 + quad * 8]);

    #pragma unroll
    for (int mt = 0; mt < 2; ++mt)
      #pragma unroll
      for (int ntd = 0; ntd < 4; ++ntd)
        O[mt][ntd] = __builtin_amdgcn_mfma_f32_16x16x32_bf16(pf[mt], vf[ntd], O[mt][ntd], 0, 0, 0);

    #pragma unroll
    for (int nt = 0; nt < 2; ++nt)
      #pragma unroll
      for (int ks = 0; ks < 2; ++ks) kf[nt][ks] = kf2[nt][ks];
    #pragma unroll
    for (int ntd = 0; ntd < 4; ++ntd) vf[ntd] = vf2[ntd];
  }

  // one deferred row-sum reduction (rows lane-aligned with O)
  #pragma unroll
  for (int off = 1; off < 16; off <<= 1)
    #pragma unroll
    for (int mt = 0; mt < 2; ++mt)
      #pragma unroll
      for (int r = 0; r < 4; ++r)
        psum[mt][r] += __shfl_xor(psum[mt][r], off);

  #pragma unroll
  for (int mt = 0; mt < 2; ++mt)
    #pragma unroll
    for (int r = 0; r < 4; ++r)
      psum[mt][r] = 1.f / psum[mt][r];
  #pragma unroll
  for (int mt = 0; mt < 2; ++mt)
    #pragma unroll
    for (int ntd = 0; ntd < 4; ++ntd)
      #pragma unroll
      for (int r = 0; r < 4; ++r)
        O[mt][ntd][r] *= psum[mt][r];

  // combine: X = O1 - softplus(lambda)*O2
  float* Of = (float*)smem_raw;               // [32][68] f32
  bf16* Xs = (bf16*)(smem_raw + 8704);        // [32][72] bf16

  __syncthreads();
  if (s == 1) {
    #pragma unroll
    for (int mt = 0; mt < 2; ++mt)
      #pragma unroll
      for (int ntd = 0; ntd < 4; ++ntd)
        #pragma unroll
        for (int r = 0; r < 4; ++r)
          Of[(mt * 16 + quad * 4 + r) * 68 + ntd * 16 + lr] = O[mt][ntd][r];
  }
  __syncthreads();
  if (s == 0) {
    float lam = log1pf(__expf(lambda_p[h]));
    #pragma unroll
    for (int mt = 0; mt < 2; ++mt)
      #pragma unroll
      for (int ntd = 0; ntd < 4; ++ntd)
        #pragma unroll
        for (int r = 0; r < 4; ++r) {
          float o2 = Of[(mt * 16 + quad * 4 + r) * 68 + ntd * 16 + lr];
          float xv = O[mt][ntd][r] - lam * o2;
          *(unsigned short*)&Xs[(mt * 16 + quad * 4 + r) * 72 + ntd * 16 + lr] = f2b(xv);
        }
  }
  __syncthreads();

  #pragma unroll
  for (int slot = 0; slot < 2; ++slot) {
    int idx = slot * 128 + t;
    int row = idx >> 3, seg = idx & 7;
    short8 xv = *reinterpret_cast<const short8*>(&Xs[row * 72 + seg * 8]);
    *reinterpret_cast<short8*>(X + (size_t)(tok0 + row) * 768 + h * 64 + seg * 8) = xv;
  }
}

// ---------------------------------------------------------------------------
extern "C" void kernel_launch(void* const* d_in, const int* in_sizes, int n_in,
                              void* d_out, int out_size, void* d_ws, size_t ws_size,
                              hipStream_t stream)
{
  const float* x        = (const float*)d_in[0];
  const float* Wq       = (const float*)d_in[1];
  const float* Wk       = (const float*)d_in[2];
  const float* Wv1      = (const float*)d_in[3];
  const float* Wv2      = (const float*)d_in[4];
  const float* lambda_p = (const float*)d_in[5];
  const float* Wo       = (const float*)d_in[6];
  const float* bo       = (const float*)d_in[7];
  float* out = (float*)d_out;

  bf16* xb   = (bf16*)d_ws;                      // 4096*768
  bf16* Wqb  = xb   + (size_t)NTOK * 768;        // 1536*768
  bf16* Wkb  = Wqb  + (size_t)1536 * 768;        // 512*768
  bf16* Wv1b = Wkb  + (size_t)512 * 768;         // 256*768
  bf16* Wv2b = Wv1b + (size_t)256 * 768;         // 256*768
  bf16* Wob  = Wv2b + (size_t)256 * 768;         // 768*768
  bf16* qb   = Wob  + (size_t)768 * 768;         // 4096*1536
  bf16* kb   = qb   + (size_t)NTOK * 1536;       // 4096*512
  bf16* v1b  = kb   + (size_t)NTOK * 512;        // 4096*256
  bf16* v2b  = v1b  + (size_t)NTOK * 256;        // 4096*256
  bf16* Xb   = v2b  + (size_t)NTOK * 256;        // 4096*768
  bf16* v1t  = Xb   + (size_t)NTOK * 768;        // 4*4*64*1024
  bf16* v2t  = v1t  + (size_t)NTOK * 256;        // 4*4*64*1024

  cvt_all<<<5568, 256, 0, stream>>>(x, Wq, Wk, Wv1, Wv2, Wo,
                                    xb, Wqb, Wkb, Wv1b, Wv2b, Wob);

  gemm_qkv<<<dim3(20, 32), 256, 0, stream>>>(xb, Wqb, Wkb, Wv1b, Wv2b,
                                             qb, kb, v1b, v2b);

  transpose_v2<<<512, 256, 0, stream>>>(v1b, v1t, v2b, v2t);

  attn_mfma<<<BATCH * NH * 32, dim3(128), 0, stream>>>(qb, kb, v1t, v2t, lambda_p, Xb);

  gemm_out<<<dim3(6, 32), 256, 0, stream>>>(Xb, Wob, out, bo);
}

// Round 6
// 187.103 us; speedup vs baseline: 2.5639x; 1.0060x over previous
//
#include <hip/hip_runtime.h>
#include <hip/hip_bf16.h>

// Sizes fixed by the problem
#define BATCH 4
#define NSEQ  1024
#define DIM   768
#define NH    12
#define NKV   4
#define HD    64
#define NTOK  (BATCH*NSEQ)   // 4096

using bf16 = __hip_bfloat16;
typedef __attribute__((ext_vector_type(8))) short short8;
typedef __attribute__((ext_vector_type(4))) float floatx4;

__device__ __forceinline__ float b2f(short x) {
  unsigned u = ((unsigned)(unsigned short)x) << 16;
  return __builtin_bit_cast(float, u);
}
__device__ __forceinline__ unsigned short f2b(float f) {
  unsigned u = __builtin_bit_cast(unsigned, f);
  unsigned r = u + 0x7FFF + ((u >> 16) & 1);   // RNE
  return (unsigned short)(r >> 16);
}

// async global->LDS, 16B per lane; LDS dest = wave-uniform base + lane*16
__device__ __forceinline__ void load_lds_16(const bf16* g, bf16* l) {
  __builtin_amdgcn_global_load_lds(
      (const __attribute__((address_space(1))) void*)g,
      (__attribute__((address_space(3))) void*)l, 16, 0, 0);
}

// ---------------------------------------------------------------------------
// Fused f32->bf16 convert of all 6 input tensors (exact sizes hardcoded).
// ---------------------------------------------------------------------------
__global__ __launch_bounds__(256) void cvt_all(
    const float* __restrict__ x,  const float* __restrict__ wq,
    const float* __restrict__ wk, const float* __restrict__ wv1,
    const float* __restrict__ wv2, const float* __restrict__ wo,
    bf16* __restrict__ xb,  bf16* __restrict__ wqb, bf16* __restrict__ wkb,
    bf16* __restrict__ wv1b, bf16* __restrict__ wv2b, bf16* __restrict__ wob)
{
  int i = blockIdx.x * 256 + threadIdx.x;   // float4 index, total 1425408
  const float* s; bf16* d; int off;
  if      (i <  786432) { s = x;   d = xb;   off = i; }
  else if (i < 1081344) { s = wq;  d = wqb;  off = i -  786432; }
  else if (i < 1179648) { s = wk;  d = wkb;  off = i - 1081344; }
  else if (i < 1228800) { s = wv1; d = wv1b; off = i - 1179648; }
  else if (i < 1277952) { s = wv2; d = wv2b; off = i - 1228800; }
  else                  { s = wo;  d = wob;  off = i - 1277952; }
  float4 f = reinterpret_cast<const float4*>(s)[off];
  ushort4 u;
  u.x = f2b(f.x); u.y = f2b(f.y); u.z = f2b(f.z); u.w = f2b(f.w);
  reinterpret_cast<ushort4*>(d)[off] = u;
}

// ---------------------------------------------------------------------------
// Fused QKV projection GEMM, 128x128 tile, BK=32, global_load_lds staging.
// grid = (20 N-tiles, 32 M-tiles). N-tiles 0-11: q (rope+norm epilogue),
// 12-15: k (rope+norm), 16-17: v1, 18-19: v2 (plain).
// Epilogue rule: NO function calls with pointer args (sincosf demoted acc
// to scratch in R4). Only inline __sinf/__cosf, constant-index scalars.
// ---------------------------------------------------------------------------
__global__ __launch_bounds__(256, 2) void gemm_qkv(
    const bf16* __restrict__ xb,
    const bf16* __restrict__ Wqb, const bf16* __restrict__ Wkb,
    const bf16* __restrict__ Wv1b, const bf16* __restrict__ Wv2b,
    bf16* __restrict__ qb, bf16* __restrict__ kb,
    bf16* __restrict__ v1b, bf16* __restrict__ v2b)
{
  __shared__ __align__(16) bf16 As[128 * 32];
  __shared__ __align__(16) bf16 Ws[128 * 32];

  const int bn = blockIdx.x, bm = blockIdx.y;
  const bf16* Wp; bf16* Yp; int ldY; bool dorope;
  if (bn < 12)      { Wp = Wqb  + (size_t)bn * 128 * 768;        Yp = qb  + bn * 128;        ldY = 1536; dorope = true; }
  else if (bn < 16) { Wp = Wkb  + (size_t)(bn - 12) * 128 * 768; Yp = kb  + (bn - 12) * 128; ldY = 512;  dorope = true; }
  else if (bn < 18) { Wp = Wv1b + (size_t)(bn - 16) * 128 * 768; Yp = v1b + (bn - 16) * 128; ldY = 256;  dorope = false; }
  else              { Wp = Wv2b + (size_t)(bn - 18) * 128 * 768; Yp = v2b + (bn - 18) * 128; ldY = 256;  dorope = false; }

  const int t = threadIdx.x, wave = t >> 6, lane = t & 63;
  const int wm = wave >> 1, wn = wave & 1;
  const int quad = lane >> 4, lr = lane & 15;

  const int srow = wave * 32 + (lane >> 2);
  const int scol = (lane & 3) * 8;
  const bf16* Ag = xb + (size_t)(bm * 128 + srow) * 768 + scol;
  const bf16* Wg = Wp + (size_t)srow * 768 + scol;
  bf16* Al0 = As + wave * 1024;
  bf16* Al1 = As + wave * 1024 + 512;
  bf16* Wl0 = Ws + wave * 1024;
  bf16* Wl1 = Ws + wave * 1024 + 512;

  floatx4 acc[4][4] = {};

  for (int k0 = 0; k0 < 768; k0 += 32) {
    load_lds_16(Ag + k0,            Al0);
    load_lds_16(Ag + 16 * 768 + k0, Al1);
    load_lds_16(Wg + k0,            Wl0);
    load_lds_16(Wg + 16 * 768 + k0, Wl1);
    __syncthreads();

    short8 af[4], wf[4];
    #pragma unroll
    for (int mt = 0; mt < 4; ++mt)
      af[mt] = *reinterpret_cast<const short8*>(&As[(wm * 64 + mt * 16 + lr) * 32 + quad * 8]);
    #pragma unroll
    for (int nt = 0; nt < 4; ++nt)
      wf[nt] = *reinterpret_cast<const short8*>(&Ws[(wn * 64 + nt * 16 + lr) * 32 + quad * 8]);

    #pragma unroll
    for (int mt = 0; mt < 4; ++mt)
      #pragma unroll
      for (int nt = 0; nt < 4; ++nt)
        acc[mt][nt] = __builtin_amdgcn_mfma_f32_16x16x32_bf16(af[mt], wf[nt], acc[mt][nt], 0, 0, 0);
    __syncthreads();
  }

  if (dorope) {
    const float K2 = 0.41524101186098309f;             // log2(10000)/32
    const float invf0 = exp2f(-(float)lr * K2);
    const float invf1 = exp2f(-(float)(16 + lr) * K2);
    const float sgn = (lr & 1) ? 1.f : -1.f;
    #pragma unroll
    for (int mt = 0; mt < 4; ++mt) {
      #pragma unroll
      for (int r = 0; r < 4; ++r) {
        int row = bm * 128 + wm * 64 + mt * 16 + quad * 4 + r;
        int n = row & (NSEQ - 1);
        float ph = (float)(n >> 5), pw = (float)(n & 31);
        float v0 = acc[mt][0][r];
        float v1 = acc[mt][1][r];
        float v2 = acc[mt][2][r];
        float v3 = acc[mt][3][r];
        float rot0 = sgn * __shfl_xor(v0, 1);
        float rot1 = sgn * __shfl_xor(v1, 1);
        float rot2 = sgn * __shfl_xor(v2, 1);
        float rot3 = sgn * __shfl_xor(v3, 1);
        float t0 = ph * invf0, t1 = ph * invf1, t2 = pw * invf0, t3 = pw * invf1;
        float rv0 = v0 * __cosf(t0) + rot0 * __sinf(t0);
        float rv1 = v1 * __cosf(t1) + rot1 * __sinf(t1);
        float rv2 = v2 * __cosf(t2) + rot2 * __sinf(t2);
        float rv3 = v3 * __cosf(t3) + rot3 * __sinf(t3);
        float ss = rv0 * rv0 + rv1 * rv1 + rv2 * rv2 + rv3 * rv3;
        #pragma unroll
        for (int off = 1; off < 16; off <<= 1) ss += __shfl_xor(ss, off);
        float sc = 1.f / (sqrtf(ss) + 1e-6f);
        size_t rbase = (size_t)row * ldY + wn * 64 + lr;
        *(unsigned short*)&Yp[rbase +  0] = f2b(rv0 * sc);
        *(unsigned short*)&Yp[rbase + 16] = f2b(rv1 * sc);
        *(unsigned short*)&Yp[rbase + 32] = f2b(rv2 * sc);
        *(unsigned short*)&Yp[rbase + 48] = f2b(rv3 * sc);
      }
    }
  } else {
    #pragma unroll
    for (int mt = 0; mt < 4; ++mt)
      #pragma unroll
      for (int nt = 0; nt < 4; ++nt)
        #pragma unroll
        for (int r = 0; r < 4; ++r) {
          int row = bm * 128 + wm * 64 + mt * 16 + quad * 4 + r;
          int col = wn * 64 + nt * 16 + lr;
          *(unsigned short*)&Yp[(size_t)row * ldY + col] = f2b(acc[mt][nt][r]);
        }
  }
}

// ---------------------------------------------------------------------------
// Final GEMM: out = X @ Wo^T + bo, f32 out, 128x128 tile, global_load_lds.
// ---------------------------------------------------------------------------
__global__ __launch_bounds__(256, 2) void gemm_out(
    const bf16* __restrict__ Xb, const bf16* __restrict__ Wob,
    float* __restrict__ out, const float* __restrict__ bias)
{
  __shared__ __align__(16) bf16 As[128 * 32];
  __shared__ __align__(16) bf16 Ws[128 * 32];

  const int bn = blockIdx.x, bm = blockIdx.y;
  const int t = threadIdx.x, wave = t >> 6, lane = t & 63;
  const int wm = wave >> 1, wn = wave & 1;
  const int quad = lane >> 4, lr = lane & 15;

  const int srow = wave * 32 + (lane >> 2);
  const int scol = (lane & 3) * 8;
  const bf16* Ag = Xb  + (size_t)(bm * 128 + srow) * 768 + scol;
  const bf16* Wg = Wob + (size_t)(bn * 128 + srow) * 768 + scol;
  bf16* Al0 = As + wave * 1024;
  bf16* Al1 = As + wave * 1024 + 512;
  bf16* Wl0 = Ws + wave * 1024;
  bf16* Wl1 = Ws + wave * 1024 + 512;

  floatx4 acc[4][4] = {};

  for (int k0 = 0; k0 < 768; k0 += 32) {
    load_lds_16(Ag + k0,            Al0);
    load_lds_16(Ag + 16 * 768 + k0, Al1);
    load_lds_16(Wg + k0,            Wl0);
    load_lds_16(Wg + 16 * 768 + k0, Wl1);
    __syncthreads();

    short8 af[4], wf[4];
    #pragma unroll
    for (int mt = 0; mt < 4; ++mt)
      af[mt] = *reinterpret_cast<const short8*>(&As[(wm * 64 + mt * 16 + lr) * 32 + quad * 8]);
    #pragma unroll
    for (int nt = 0; nt < 4; ++nt)
      wf[nt] = *reinterpret_cast<const short8*>(&Ws[(wn * 64 + nt * 16 + lr) * 32 + quad * 8]);

    #pragma unroll
    for (int mt = 0; mt < 4; ++mt)
      #pragma unroll
      for (int nt = 0; nt < 4; ++nt)
        acc[mt][nt] = __builtin_amdgcn_mfma_f32_16x16x32_bf16(af[mt], wf[nt], acc[mt][nt], 0, 0, 0);
    __syncthreads();
  }

  #pragma unroll
  for (int nt = 0; nt < 4; ++nt) {
    int col = bn * 128 + wn * 64 + nt * 16 + lr;
    float bv = bias[col];
    #pragma unroll
    for (int mt = 0; mt < 4; ++mt)
      #pragma unroll
      for (int r = 0; r < 4; ++r) {
        int row = bm * 128 + wm * 64 + mt * 16 + quad * 4 + r;
        out[(size_t)row * 768 + col] = acc[mt][nt][r] + bv;
      }
  }
}

// ---------------------------------------------------------------------------
// V transpose (both streams in one launch):
// v[4096 tok][256] -> vt[b][kvh][64 d][1024 n]
// ---------------------------------------------------------------------------
__global__ __launch_bounds__(256) void transpose_v2(
    const bf16* __restrict__ v1, bf16* __restrict__ v1t,
    const bf16* __restrict__ v2, bf16* __restrict__ v2t)
{
  __shared__ bf16 tile[64][68];
  int blk = blockIdx.x;
  const bf16* v  = (blk >= 256) ? v2  : v1;
  bf16*       vt = (blk >= 256) ? v2t : v1t;
  blk &= 255;
  int ntile = blk & 15;
  int kvh = (blk >> 4) & 3;
  int b = blk >> 6;
  int t = threadIdx.x;
  int n0 = ntile * 64;

  #pragma unroll
  for (int l = 0; l < 4; ++l) {
    int nl = (t >> 4) + l * 16;
    int dl = (t & 15) * 4;
    ushort4 val = *reinterpret_cast<const ushort4*>(
        v + (size_t)(b * 1024 + n0 + nl) * 256 + kvh * 64 + dl);
    *reinterpret_cast<ushort4*>(&tile[nl][dl]) = val;
  }
  __syncthreads();
  #pragma unroll
  for (int l = 0; l < 4; ++l) {
    int dl = (t >> 4) + l * 16;
    int nl = (t & 15) * 4;
    ushort4 val;
    val.x = *(const unsigned short*)&tile[nl + 0][dl];
    val.y = *(const unsigned short*)&tile[nl + 1][dl];
    val.z = *(const unsigned short*)&tile[nl + 2][dl];
    val.w = *(const unsigned short*)&tile[nl + 3][dl];
    *reinterpret_cast<ushort4*>(
        vt + (size_t)((b * 4 + kvh) * 64 + dl) * 1024 + n0 + nl) = val;
  }
}

// ---------------------------------------------------------------------------
// MFMA flash attention v2: 4 waves/block = (stream s, kh-half). Each wave
// accumulates partial O/psum over half the kh window (legal: no softmax max
// since unit-norm q,k bound scores to [-1/8,1/8]); partials combined via
// conflict-free LDS slabs. 2-buffer prefetch, no register copies.
// ---------------------------------------------------------------------------
struct Frag { short8 kf[2][2]; short8 vf[4]; };

__device__ __forceinline__ void attn_load(
    Frag& f, const bf16* __restrict__ k, const bf16* __restrict__ vbase,
    int tkbase, int kh, int soff, int kvh, int lr, int quad)
{
  const int tk0 = tkbase + kh * 32;
  #pragma unroll
  for (int nt = 0; nt < 2; ++nt)
    #pragma unroll
    for (int ks = 0; ks < 2; ++ks)
      f.kf[nt][ks] = *reinterpret_cast<const short8*>(
          k + (size_t)(tk0 + nt * 16 + lr) * 512 + soff + kvh * 64 + ks * 32 + quad * 8);
  #pragma unroll
  for (int ntd = 0; ntd < 4; ++ntd)
    f.vf[ntd] = *reinterpret_cast<const short8*>(
        vbase + (size_t)(ntd * 16 + lr) * 1024 + kh * 32 + quad * 8);
}

__device__ __forceinline__ void attn_step(
    const short8 (&qf)[2][2], const Frag& f, unsigned maskbits,
    floatx4 (&O)[2][4], float (&psum)[2][4], bf16* __restrict__ Pl,
    int quad, int lr)
{
  floatx4 S[2][2] = {};
  #pragma unroll
  for (int ks = 0; ks < 2; ++ks) {
    S[0][0] = __builtin_amdgcn_mfma_f32_16x16x32_bf16(qf[0][ks], f.kf[0][ks], S[0][0], 0, 0, 0);
    S[0][1] = __builtin_amdgcn_mfma_f32_16x16x32_bf16(qf[0][ks], f.kf[1][ks], S[0][1], 0, 0, 0);
    S[1][0] = __builtin_amdgcn_mfma_f32_16x16x32_bf16(qf[1][ks], f.kf[0][ks], S[1][0], 0, 0, 0);
    S[1][1] = __builtin_amdgcn_mfma_f32_16x16x32_bf16(qf[1][ks], f.kf[1][ks], S[1][1], 0, 0, 0);
  }

  #pragma unroll
  for (int mt = 0; mt < 2; ++mt)
    #pragma unroll
    for (int nt = 0; nt < 2; ++nt)
      #pragma unroll
      for (int r = 0; r < 4; ++r) {
        float p = __expf(S[mt][nt][r] * 0.125f);
        p = ((maskbits >> (mt * 8 + nt * 4 + r)) & 1u) ? p : 0.0f;
        psum[mt][r] += p;
        *(unsigned short*)&Pl[(mt * 16 + quad * 4 + r) * 40 + nt * 16 + lr] = f2b(p);
      }

  short8 pf0 = *reinterpret_cast<const short8*>(&Pl[(lr) * 40 + quad * 8]);
  short8 pf1 = *reinterpret_cast<const short8*>(&Pl[(16 + lr) * 40 + quad * 8]);
  #pragma unroll
  for (int ntd = 0; ntd < 4; ++ntd) {
    O[0][ntd] = __builtin_amdgcn_mfma_f32_16x16x32_bf16(pf0, f.vf[ntd], O[0][ntd], 0, 0, 0);
    O[1][ntd] = __builtin_amdgcn_mfma_f32_16x16x32_bf16(pf1, f.vf[ntd], O[1][ntd], 0, 0, 0);
  }
}

__global__ __launch_bounds__(256, 2) void attn_mfma(
    const bf16* __restrict__ q, const bf16* __restrict__ k,
    const bf16* __restrict__ v1t, const bf16* __restrict__ v2t,
    const float* __restrict__ lambda_p, bf16* __restrict__ X)
{
  // LDS map: [0,10240) P staging (4 waves x 2560B)
  //          [10240,26624) O slabs (2 streams x 8192B, lane-stride 16B)
  //          [26624,30720) psum slabs (2 x 2048B)
  //          [30720,35328) X staging [32][72] bf16
  __shared__ __align__(16) char smem[35328];

  const int bid = blockIdx.x;
  const int qh = bid & 31;
  const int hb = bid >> 5;          // h + 12*b
  const int h  = hb % 12;
  const int b  = hb / 12;
  const int kvh = h / 3;

  const int t = threadIdx.x;
  const int w = t >> 6;             // 0..3
  const int s = w >> 1;             // stream
  const int half = w & 1;           // kh half
  const int lane = t & 63;
  const int quad = lane >> 4, lr = lane & 15;

  bf16* Pl = (bf16*)(smem + w * 2560);
  float* Oslab = (float*)(smem + 10240 + s * 8192);
  float* Pslab = (float*)(smem + 26624 + s * 2048);
  bf16* Xs = (bf16*)(smem + 30720);

  const int tok0 = b * NSEQ + qh * 32;
  const int soff = s * 256;

  // Q fragments: A[m=lr (+16mt)][k=quad*8+j (+32ks)]
  short8 qf[2][2];
  #pragma unroll
  for (int mt = 0; mt < 2; ++mt)
    #pragma unroll
    for (int ks = 0; ks < 2; ++ks)
      qf[mt][ks] = *reinterpret_cast<const short8*>(
          q + (size_t)(tok0 + mt * 16 + lr) * 1536 + s * 768 + h * 64 + ks * 32 + quad * 8);

  // window mask bits: bit(mt*8+nt*4+r) = |q - km| <= 8
  unsigned maskbits = 0;
  #pragma unroll
  for (int mt = 0; mt < 2; ++mt)
    #pragma unroll
    for (int nt = 0; nt < 2; ++nt)
      #pragma unroll
      for (int r = 0; r < 4; ++r) {
        int qq = mt * 16 + quad * 4 + r;
        int km = nt * 16 + lr;
        int d = km - qq; if (d < 0) d = -d;
        if (d <= 8) maskbits |= 1u << (mt * 8 + nt * 4 + r);
      }

  floatx4 O[2][4] = {};
  float psum[2][4] = {};

  const int kh0 = (qh > 8) ? qh - 8 : 0;
  const int kh1 = (qh < 23) ? qh + 8 : 31;
  const int cnt = kh1 - kh0 + 1;              // 9..17 -> both halves nonempty
  const int cA = (cnt + 1) >> 1;
  const int khA = half ? kh0 + cA : kh0;
  const int khB = half ? kh1 : kh0 + cA - 1;

  const bf16* vbase = (s ? v2t : v1t) + (size_t)((b * 4 + kvh) * 64) * 1024;
  const int tkbase = b * NSEQ;

  Frag fA, fB;
  attn_load(fA, k, vbase, tkbase, khA, soff, kvh, lr, quad);
  attn_load(fB, k, vbase, tkbase, (khA + 1 <= khB) ? khA + 1 : khB, soff, kvh, lr, quad);

  int i = khA;
  while (true) {
    attn_step(qf, fA, maskbits, O, psum, Pl, quad, lr);
    if (i == khB) break;
    ++i;
    attn_load(fA, k, vbase, tkbase, (i + 1 <= khB) ? i + 1 : i, soff, kvh, lr, quad);
    attn_step(qf, fB, maskbits, O, psum, Pl, quad, lr);
    if (i == khB) break;
    ++i;
    attn_load(fB, k, vbase, tkbase, (i + 1 <= khB) ? i + 1 : i, soff, kvh, lr, quad);
  }

  // ---- combine the two kh-halves per stream (linear: no softmax rescale) ----
  __syncthreads();
  if (half == 1) {
    #pragma unroll
    for (int mt = 0; mt < 2; ++mt)
      #pragma unroll
      for (int ntd = 0; ntd < 4; ++ntd)
        *reinterpret_cast<floatx4*>(&Oslab[(mt * 4 + ntd) * 256 + lane * 4]) = O[mt][ntd];
    floatx4 p0, p1;
    p0[0] = psum[0][0]; p0[1] = psum[0][1]; p0[2] = psum[0][2]; p0[3] = psum[0][3];
    p1[0] = psum[1][0]; p1[1] = psum[1][1]; p1[2] = psum[1][2]; p1[3] = psum[1][3];
    *reinterpret_cast<floatx4*>(&Pslab[lane * 4])       = p0;
    *reinterpret_cast<floatx4*>(&Pslab[256 + lane * 4]) = p1;
  }
  __syncthreads();
  if (half == 0) {
    #pragma unroll
    for (int mt = 0; mt < 2; ++mt)
      #pragma unroll
      for (int ntd = 0; ntd < 4; ++ntd)
        O[mt][ntd] += *reinterpret_cast<const floatx4*>(&Oslab[(mt * 4 + ntd) * 256 + lane * 4]);
    floatx4 p0 = *reinterpret_cast<const floatx4*>(&Pslab[lane * 4]);
    floatx4 p1 = *reinterpret_cast<const floatx4*>(&Pslab[256 + lane * 4]);
    #pragma unroll
    for (int r = 0; r < 4; ++r) { psum[0][r] += p0[r]; psum[1][r] += p1[r]; }

    // row-sum reduce over the 16 lr lanes, then normalize
    #pragma unroll
    for (int off = 1; off < 16; off <<= 1)
      #pragma unroll
      for (int mt = 0; mt < 2; ++mt)
        #pragma unroll
        for (int r = 0; r < 4; ++r)
          psum[mt][r] += __shfl_xor(psum[mt][r], off);
    #pragma unroll
    for (int mt = 0; mt < 2; ++mt)
      #pragma unroll
      for (int r = 0; r < 4; ++r)
        psum[mt][r] = 1.f / psum[mt][r];
    #pragma unroll
    for (int mt = 0; mt < 2; ++mt)
      #pragma unroll
      for (int ntd = 0; ntd < 4; ++ntd)
        #pragma unroll
        for (int r = 0; r < 4; ++r)
          O[mt][ntd][r] *= psum[mt][r];

    if (s == 1) {   // publish normalized O2
      #pragma unroll
      for (int mt = 0; mt < 2; ++mt)
        #pragma unroll
        for (int ntd = 0; ntd < 4; ++ntd)
          *reinterpret_cast<floatx4*>(&Oslab[(mt * 4 + ntd) * 256 + lane * 4]) = O[mt][ntd];
    }
  }
  __syncthreads();
  if (w == 0) {     // s=0, half=0: differential combine
    float lam = log1pf(__expf(lambda_p[h]));
    const float* O2slab = (const float*)(smem + 10240 + 8192);
    #pragma unroll
    for (int mt = 0; mt < 2; ++mt)
      #pragma unroll
      for (int ntd = 0; ntd < 4; ++ntd) {
        floatx4 o2 = *reinterpret_cast<const floatx4*>(&O2slab[(mt * 4 + ntd) * 256 + lane * 4]);
        #pragma unroll
        for (int r = 0; r < 4; ++r) {
          float xv = O[mt][ntd][r] - lam * o2[r];
          *(unsigned short*)&Xs[(mt * 16 + quad * 4 + r) * 72 + ntd * 16 + lr] = f2b(xv);
        }
      }
  }
  __syncthreads();

  // coalesced store of the 32x64 bf16 tile (256 thr = 32 rows x 8 segs)
  {
    int row = t >> 3, seg = t & 7;
    short8 xv = *reinterpret_cast<const short8*>(&Xs[row * 72 + seg * 8]);
    *reinterpret_cast<short8*>(X + (size_t)(tok0 + row) * 768 + h * 64 + seg * 8) = xv;
  }
}

// ---------------------------------------------------------------------------
extern "C" void kernel_launch(void* const* d_in, const int* in_sizes, int n_in,
                              void* d_out, int out_size, void* d_ws, size_t ws_size,
                              hipStream_t stream)
{
  const float* x        = (const float*)d_in[0];
  const float* Wq       = (const float*)d_in[1];
  const float* Wk       = (const float*)d_in[2];
  const float* Wv1      = (const float*)d_in[3];
  const float* Wv2      = (const float*)d_in[4];
  const float* lambda_p = (const float*)d_in[5];
  const float* Wo       = (const float*)d_in[6];
  const float* bo       = (const float*)d_in[7];
  float* out = (float*)d_out;

  bf16* xb   = (bf16*)d_ws;                      // 4096*768
  bf16* Wqb  = xb   + (size_t)NTOK * 768;        // 1536*768
  bf16* Wkb  = Wqb  + (size_t)1536 * 768;        // 512*768
  bf16* Wv1b = Wkb  + (size_t)512 * 768;         // 256*768
  bf16* Wv2b = Wv1b + (size_t)256 * 768;         // 256*768
  bf16* Wob  = Wv2b + (size_t)256 * 768;         // 768*768
  bf16* qb   = Wob  + (size_t)768 * 768;         // 4096*1536
  bf16* kb   = qb   + (size_t)NTOK * 1536;       // 4096*512
  bf16* v1b  = kb   + (size_t)NTOK * 512;        // 4096*256
  bf16* v2b  = v1b  + (size_t)NTOK * 256;        // 4096*256
  bf16* Xb   = v2b  + (size_t)NTOK * 256;        // 4096*768
  bf16* v1t  = Xb   + (size_t)NTOK * 768;        // 4*4*64*1024
  bf16* v2t  = v1t  + (size_t)NTOK * 256;        // 4*4*64*1024

  cvt_all<<<5568, 256, 0, stream>>>(x, Wq, Wk, Wv1, Wv2, Wo,
                                    xb, Wqb, Wkb, Wv1b, Wv2b, Wob);

  gemm_qkv<<<dim3(20, 32), 256, 0, stream>>>(xb, Wqb, Wkb, Wv1b, Wv2b,
                                             qb, kb, v1b, v2b);

  transpose_v2<<<512, 256, 0, stream>>>(v1b, v1t, v2b, v2t);

  attn_mfma<<<BATCH * NH * 32, 256, 0, stream>>>(qb, kb, v1t, v2t, lambda_p, Xb);

  gemm_out<<<dim3(6, 32), 256, 0, stream>>>(Xb, Wob, out, bo);
}

// Round 7
// 163.620 us; speedup vs baseline: 2.9319x; 1.1435x over previous
//
#include <hip/hip_runtime.h>
#include <hip/hip_bf16.h>

// Sizes fixed by the problem
#define BATCH 4
#define NSEQ  1024
#define DIM   768
#define NH    12
#define NKV   4
#define HD    64
#define NTOK  (BATCH*NSEQ)   // 4096

using bf16 = __hip_bfloat16;
typedef __attribute__((ext_vector_type(8))) short short8;
typedef __attribute__((ext_vector_type(4))) float floatx4;

__device__ __forceinline__ float b2f(short x) {
  unsigned u = ((unsigned)(unsigned short)x) << 16;
  return __builtin_bit_cast(float, u);
}
__device__ __forceinline__ unsigned short f2b(float f) {
  unsigned u = __builtin_bit_cast(unsigned, f);
  unsigned r = u + 0x7FFF + ((u >> 16) & 1);   // RNE
  return (unsigned short)(r >> 16);
}

// async global->LDS, 16B per lane; LDS dest = wave-uniform base + lane*16
__device__ __forceinline__ void load_lds_16(const bf16* g, bf16* l) {
  __builtin_amdgcn_global_load_lds(
      (const __attribute__((address_space(1))) void*)g,
      (__attribute__((address_space(3))) void*)l, 16, 0, 0);
}

// ---------------------------------------------------------------------------
// Fused f32->bf16 convert of all 6 input tensors (exact sizes hardcoded).
// ---------------------------------------------------------------------------
__global__ __launch_bounds__(256) void cvt_all(
    const float* __restrict__ x,  const float* __restrict__ wq,
    const float* __restrict__ wk, const float* __restrict__ wv1,
    const float* __restrict__ wv2, const float* __restrict__ wo,
    bf16* __restrict__ xb,  bf16* __restrict__ wqb, bf16* __restrict__ wkb,
    bf16* __restrict__ wv1b, bf16* __restrict__ wv2b, bf16* __restrict__ wob)
{
  int i = blockIdx.x * 256 + threadIdx.x;   // float4 index, total 1425408
  const float* s; bf16* d; int off;
  if      (i <  786432) { s = x;   d = xb;   off = i; }
  else if (i < 1081344) { s = wq;  d = wqb;  off = i -  786432; }
  else if (i < 1179648) { s = wk;  d = wkb;  off = i - 1081344; }
  else if (i < 1228800) { s = wv1; d = wv1b; off = i - 1179648; }
  else if (i < 1277952) { s = wv2; d = wv2b; off = i - 1228800; }
  else                  { s = wo;  d = wob;  off = i - 1277952; }
  float4 f = reinterpret_cast<const float4*>(s)[off];
  ushort4 u;
  u.x = f2b(f.x); u.y = f2b(f.y); u.z = f2b(f.z); u.w = f2b(f.w);
  reinterpret_cast<ushort4*>(d)[off] = u;
}

// ---------------------------------------------------------------------------
// Fused QKV projection GEMM, 128x128 tile, BK=32, global_load_lds staging.
// grid = (20 N-tiles, 32 M-tiles). N-tiles 0-11: q (rope+norm epilogue),
// 12-15: k (rope+norm), 16-17: v1, 18-19: v2 (plain).
// Epilogue rule: NO function calls with pointer args (sincosf demoted acc
// to scratch in R4). Only inline __sinf/__cosf, constant-index scalars.
// ---------------------------------------------------------------------------
__global__ __launch_bounds__(256, 2) void gemm_qkv(
    const bf16* __restrict__ xb,
    const bf16* __restrict__ Wqb, const bf16* __restrict__ Wkb,
    const bf16* __restrict__ Wv1b, const bf16* __restrict__ Wv2b,
    bf16* __restrict__ qb, bf16* __restrict__ kb,
    bf16* __restrict__ v1b, bf16* __restrict__ v2b)
{
  __shared__ __align__(16) bf16 As[128 * 32];
  __shared__ __align__(16) bf16 Ws[128 * 32];

  const int bn = blockIdx.x, bm = blockIdx.y;
  const bf16* Wp; bf16* Yp; int ldY; bool dorope;
  if (bn < 12)      { Wp = Wqb  + (size_t)bn * 128 * 768;        Yp = qb  + bn * 128;        ldY = 1536; dorope = true; }
  else if (bn < 16) { Wp = Wkb  + (size_t)(bn - 12) * 128 * 768; Yp = kb  + (bn - 12) * 128; ldY = 512;  dorope = true; }
  else if (bn < 18) { Wp = Wv1b + (size_t)(bn - 16) * 128 * 768; Yp = v1b + (bn - 16) * 128; ldY = 256;  dorope = false; }
  else              { Wp = Wv2b + (size_t)(bn - 18) * 128 * 768; Yp = v2b + (bn - 18) * 128; ldY = 256;  dorope = false; }

  const int t = threadIdx.x, wave = t >> 6, lane = t & 63;
  const int wm = wave >> 1, wn = wave & 1;
  const int quad = lane >> 4, lr = lane & 15;

  const int srow = wave * 32 + (lane >> 2);
  const int scol = (lane & 3) * 8;
  const bf16* Ag = xb + (size_t)(bm * 128 + srow) * 768 + scol;
  const bf16* Wg = Wp + (size_t)srow * 768 + scol;
  bf16* Al0 = As + wave * 1024;
  bf16* Al1 = As + wave * 1024 + 512;
  bf16* Wl0 = Ws + wave * 1024;
  bf16* Wl1 = Ws + wave * 1024 + 512;

  floatx4 acc[4][4] = {};

  for (int k0 = 0; k0 < 768; k0 += 32) {
    load_lds_16(Ag + k0,            Al0);
    load_lds_16(Ag + 16 * 768 + k0, Al1);
    load_lds_16(Wg + k0,            Wl0);
    load_lds_16(Wg + 16 * 768 + k0, Wl1);
    __syncthreads();

    short8 af[4], wf[4];
    #pragma unroll
    for (int mt = 0; mt < 4; ++mt)
      af[mt] = *reinterpret_cast<const short8*>(&As[(wm * 64 + mt * 16 + lr) * 32 + quad * 8]);
    #pragma unroll
    for (int nt = 0; nt < 4; ++nt)
      wf[nt] = *reinterpret_cast<const short8*>(&Ws[(wn * 64 + nt * 16 + lr) * 32 + quad * 8]);

    #pragma unroll
    for (int mt = 0; mt < 4; ++mt)
      #pragma unroll
      for (int nt = 0; nt < 4; ++nt)
        acc[mt][nt] = __builtin_amdgcn_mfma_f32_16x16x32_bf16(af[mt], wf[nt], acc[mt][nt], 0, 0, 0);
    __syncthreads();
  }

  if (dorope) {
    const float K2 = 0.41524101186098309f;             // log2(10000)/32
    const float invf0 = exp2f(-(float)lr * K2);
    const float invf1 = exp2f(-(float)(16 + lr) * K2);
    const float sgn = (lr & 1) ? 1.f : -1.f;
    #pragma unroll
    for (int mt = 0; mt < 4; ++mt) {
      #pragma unroll
      for (int r = 0; r < 4; ++r) {
        int row = bm * 128 + wm * 64 + mt * 16 + quad * 4 + r;
        int n = row & (NSEQ - 1);
        float ph = (float)(n >> 5), pw = (float)(n & 31);
        float v0 = acc[mt][0][r];
        float v1 = acc[mt][1][r];
        float v2 = acc[mt][2][r];
        float v3 = acc[mt][3][r];
        float rot0 = sgn * __shfl_xor(v0, 1);
        float rot1 = sgn * __shfl_xor(v1, 1);
        float rot2 = sgn * __shfl_xor(v2, 1);
        float rot3 = sgn * __shfl_xor(v3, 1);
        float t0 = ph * invf0, t1 = ph * invf1, t2 = pw * invf0, t3 = pw * invf1;
        float rv0 = v0 * __cosf(t0) + rot0 * __sinf(t0);
        float rv1 = v1 * __cosf(t1) + rot1 * __sinf(t1);
        float rv2 = v2 * __cosf(t2) + rot2 * __sinf(t2);
        float rv3 = v3 * __cosf(t3) + rot3 * __sinf(t3);
        float ss = rv0 * rv0 + rv1 * rv1 + rv2 * rv2 + rv3 * rv3;
        #pragma unroll
        for (int off = 1; off < 16; off <<= 1) ss += __shfl_xor(ss, off);
        float sc = 1.f / (sqrtf(ss) + 1e-6f);
        size_t rbase = (size_t)row * ldY + wn * 64 + lr;
        *(unsigned short*)&Yp[rbase +  0] = f2b(rv0 * sc);
        *(unsigned short*)&Yp[rbase + 16] = f2b(rv1 * sc);
        *(unsigned short*)&Yp[rbase + 32] = f2b(rv2 * sc);
        *(unsigned short*)&Yp[rbase + 48] = f2b(rv3 * sc);
      }
    }
  } else {
    #pragma unroll
    for (int mt = 0; mt < 4; ++mt)
      #pragma unroll
      for (int nt = 0; nt < 4; ++nt)
        #pragma unroll
        for (int r = 0; r < 4; ++r) {
          int row = bm * 128 + wm * 64 + mt * 16 + quad * 4 + r;
          int col = wn * 64 + nt * 16 + lr;
          *(unsigned short*)&Yp[(size_t)row * ldY + col] = f2b(acc[mt][nt][r]);
        }
  }
}

// ---------------------------------------------------------------------------
// Final GEMM: out = X @ Wo^T + bo, f32 out, 128x128 tile, global_load_lds.
// ---------------------------------------------------------------------------
__global__ __launch_bounds__(256, 2) void gemm_out(
    const bf16* __restrict__ Xb, const bf16* __restrict__ Wob,
    float* __restrict__ out, const float* __restrict__ bias)
{
  __shared__ __align__(16) bf16 As[128 * 32];
  __shared__ __align__(16) bf16 Ws[128 * 32];

  const int bn = blockIdx.x, bm = blockIdx.y;
  const int t = threadIdx.x, wave = t >> 6, lane = t & 63;
  const int wm = wave >> 1, wn = wave & 1;
  const int quad = lane >> 4, lr = lane & 15;

  const int srow = wave * 32 + (lane >> 2);
  const int scol = (lane & 3) * 8;
  const bf16* Ag = Xb  + (size_t)(bm * 128 + srow) * 768 + scol;
  const bf16* Wg = Wob + (size_t)(bn * 128 + srow) * 768 + scol;
  bf16* Al0 = As + wave * 1024;
  bf16* Al1 = As + wave * 1024 + 512;
  bf16* Wl0 = Ws + wave * 1024;
  bf16* Wl1 = Ws + wave * 1024 + 512;

  floatx4 acc[4][4] = {};

  for (int k0 = 0; k0 < 768; k0 += 32) {
    load_lds_16(Ag + k0,            Al0);
    load_lds_16(Ag + 16 * 768 + k0, Al1);
    load_lds_16(Wg + k0,            Wl0);
    load_lds_16(Wg + 16 * 768 + k0, Wl1);
    __syncthreads();

    short8 af[4], wf[4];
    #pragma unroll
    for (int mt = 0; mt < 4; ++mt)
      af[mt] = *reinterpret_cast<const short8*>(&As[(wm * 64 + mt * 16 + lr) * 32 + quad * 8]);
    #pragma unroll
    for (int nt = 0; nt < 4; ++nt)
      wf[nt] = *reinterpret_cast<const short8*>(&Ws[(wn * 64 + nt * 16 + lr) * 32 + quad * 8]);

    #pragma unroll
    for (int mt = 0; mt < 4; ++mt)
      #pragma unroll
      for (int nt = 0; nt < 4; ++nt)
        acc[mt][nt] = __builtin_amdgcn_mfma_f32_16x16x32_bf16(af[mt], wf[nt], acc[mt][nt], 0, 0, 0);
    __syncthreads();
  }

  #pragma unroll
  for (int nt = 0; nt < 4; ++nt) {
    int col = bn * 128 + wn * 64 + nt * 16 + lr;
    float bv = bias[col];
    #pragma unroll
    for (int mt = 0; mt < 4; ++mt)
      #pragma unroll
      for (int r = 0; r < 4; ++r) {
        int row = bm * 128 + wm * 64 + mt * 16 + quad * 4 + r;
        out[(size_t)row * 768 + col] = acc[mt][nt][r] + bv;
      }
  }
}

// ---------------------------------------------------------------------------
// Repack K and V into MFMA-fragment-ordered 4KB tiles so the attention hot
// loop reads are perfectly coalesced (base + lane*16B).
// Kpk tile (b,s,kvh,kh): elem(nt,ks,quad,lr,j) = K[b*1024+kh*32+nt*16+lr]
//                                                 [s*256+kvh*64+ks*32+quad*8+j]
// Vpk tile (b,kvh,kh):   elem(ntd,quad,lr,j)   = V[b*1024+kh*32+quad*8+j]
//                                                 [kvh*64+ntd*16+lr]
// blocks 0-1023: K tiles; 1024-2047: V tiles (both streams).
// ---------------------------------------------------------------------------
__global__ __launch_bounds__(256) void repack_kv(
    const bf16* __restrict__ kb,
    const bf16* __restrict__ v1b, const bf16* __restrict__ v2b,
    bf16* __restrict__ Kpk, bf16* __restrict__ Vpk1, bf16* __restrict__ Vpk2)
{
  int blk = blockIdx.x;
  int t = threadIdx.x;
  if (blk < 1024) {
    // blk = ((b*2+s)*4+kvh)*32 + kh
    int kh = blk & 31;
    int kvh = (blk >> 5) & 3;
    int sb = blk >> 7;
    int s = sb & 1, b = sb >> 1;
    int nt = t >> 7, ks = (t >> 6) & 1, quad = (t >> 4) & 3, lr = t & 15;
    const bf16* src = kb + (size_t)(b * 1024 + kh * 32 + nt * 16 + lr) * 512
                         + s * 256 + kvh * 64 + ks * 32 + quad * 8;
    short8 v = *reinterpret_cast<const short8*>(src);
    *reinterpret_cast<short8*>(Kpk + (size_t)blk * 2048 + t * 8) = v;
  } else {
    int id = blk - 1024;
    int s = id >> 9;
    int rem = id & 511;                  // (b*4+kvh)*32 + kh
    int kh = rem & 31;
    int kvh = (rem >> 5) & 3;
    int b = rem >> 7;
    const bf16* vsrc = s ? v2b : v1b;
    bf16* vdst = s ? Vpk2 : Vpk1;
    int quad = (t >> 4) & 3, lr = t & 15;
    const bf16* base = vsrc + (size_t)(b * 1024 + kh * 32 + quad * 8) * 256
                            + kvh * 64 + (t >> 6) * 16 + lr;
    short8 o;
    #pragma unroll
    for (int j = 0; j < 8; ++j) o[j] = *(const short*)(base + j * 256);
    *reinterpret_cast<short8*>(vdst + (size_t)rem * 2048 + t * 8) = o;
  }
}

// ---------------------------------------------------------------------------
// MFMA flash attention v3: 4 waves/block = (stream s, kh-half). All K/V
// fragment loads are coalesced (packed tiles, base + lane*16B). No softmax
// max/rescale (unit-norm q,k bound scores); partials combined via LDS.
// LDS overlays loop-phase P staging with combine-phase slabs (25088 B).
// ---------------------------------------------------------------------------
struct Frag { short8 kf[2][2]; short8 vf[4]; };

__device__ __forceinline__ void attn_load(
    Frag& f, const bf16* __restrict__ kp, const bf16* __restrict__ vp,
    int kh, int lane8)
{
  const bf16* kt = kp + (size_t)kh * 2048 + lane8;
  const bf16* vt = vp + (size_t)kh * 2048 + lane8;
  f.kf[0][0] = *reinterpret_cast<const short8*>(kt);
  f.kf[0][1] = *reinterpret_cast<const short8*>(kt + 512);
  f.kf[1][0] = *reinterpret_cast<const short8*>(kt + 1024);
  f.kf[1][1] = *reinterpret_cast<const short8*>(kt + 1536);
  f.vf[0] = *reinterpret_cast<const short8*>(vt);
  f.vf[1] = *reinterpret_cast<const short8*>(vt + 512);
  f.vf[2] = *reinterpret_cast<const short8*>(vt + 1024);
  f.vf[3] = *reinterpret_cast<const short8*>(vt + 1536);
}

__device__ __forceinline__ void attn_step(
    const short8 (&qf)[2][2], const Frag& f, unsigned maskbits,
    floatx4 (&O)[2][4], float (&psum)[2][4], bf16* __restrict__ Pl,
    int quad, int lr)
{
  floatx4 S[2][2] = {};
  #pragma unroll
  for (int ks = 0; ks < 2; ++ks) {
    S[0][0] = __builtin_amdgcn_mfma_f32_16x16x32_bf16(qf[0][ks], f.kf[0][ks], S[0][0], 0, 0, 0);
    S[0][1] = __builtin_amdgcn_mfma_f32_16x16x32_bf16(qf[0][ks], f.kf[1][ks], S[0][1], 0, 0, 0);
    S[1][0] = __builtin_amdgcn_mfma_f32_16x16x32_bf16(qf[1][ks], f.kf[0][ks], S[1][0], 0, 0, 0);
    S[1][1] = __builtin_amdgcn_mfma_f32_16x16x32_bf16(qf[1][ks], f.kf[1][ks], S[1][1], 0, 0, 0);
  }

  #pragma unroll
  for (int mt = 0; mt < 2; ++mt)
    #pragma unroll
    for (int nt = 0; nt < 2; ++nt)
      #pragma unroll
      for (int r = 0; r < 4; ++r) {
        float p = __expf(S[mt][nt][r] * 0.125f);
        p = ((maskbits >> (mt * 8 + nt * 4 + r)) & 1u) ? p : 0.0f;
        psum[mt][r] += p;
        *(unsigned short*)&Pl[(mt * 16 + quad * 4 + r) * 40 + nt * 16 + lr] = f2b(p);
      }

  short8 pf0 = *reinterpret_cast<const short8*>(&Pl[(lr) * 40 + quad * 8]);
  short8 pf1 = *reinterpret_cast<const short8*>(&Pl[(16 + lr) * 40 + quad * 8]);
  #pragma unroll
  for (int ntd = 0; ntd < 4; ++ntd) {
    O[0][ntd] = __builtin_amdgcn_mfma_f32_16x16x32_bf16(pf0, f.vf[ntd], O[0][ntd], 0, 0, 0);
    O[1][ntd] = __builtin_amdgcn_mfma_f32_16x16x32_bf16(pf1, f.vf[ntd], O[1][ntd], 0, 0, 0);
  }
}

__global__ __launch_bounds__(256, 2) void attn_mfma(
    const bf16* __restrict__ q, const bf16* __restrict__ Kpk,
    const bf16* __restrict__ Vpk1, const bf16* __restrict__ Vpk2,
    const float* __restrict__ lambda_p, bf16* __restrict__ X)
{
  // Loop phase:    [0,10240)  P staging (4 waves x 2560B)
  // Combine phase: [0,16384)  O slabs (2 streams x 8192B)
  //                [16384,20480) psum slabs (2 x 2048B)
  //                [20480,25088) X staging [32][72] bf16
  __shared__ __align__(16) char smem[25088];

  const int bid = blockIdx.x;
  const int qh = bid & 31;
  const int hb = bid >> 5;          // h + 12*b
  const int h  = hb % 12;
  const int b  = hb / 12;
  const int kvh = h / 3;

  const int t = threadIdx.x;
  const int w = t >> 6;             // 0..3
  const int s = w >> 1;             // stream
  const int half = w & 1;           // kh half
  const int lane = t & 63;
  const int quad = lane >> 4, lr = lane & 15;
  const int lane8 = lane * 8;

  bf16* Pl = (bf16*)(smem + w * 2560);
  float* Oslab = (float*)(smem + s * 8192);
  float* Pslab = (float*)(smem + 16384 + s * 2048);
  bf16* Xs = (bf16*)(smem + 20480);

  const int tok0 = b * NSEQ + qh * 32;

  // Q fragments: A[m=lr (+16mt)][k=quad*8+j (+32ks)]
  short8 qf[2][2];
  #pragma unroll
  for (int mt = 0; mt < 2; ++mt)
    #pragma unroll
    for (int ks = 0; ks < 2; ++ks)
      qf[mt][ks] = *reinterpret_cast<const short8*>(
          q + (size_t)(tok0 + mt * 16 + lr) * 1536 + s * 768 + h * 64 + ks * 32 + quad * 8);

  // window mask bits: bit(mt*8+nt*4+r) = |q - km| <= 8
  unsigned maskbits = 0;
  #pragma unroll
  for (int mt = 0; mt < 2; ++mt)
    #pragma unroll
    for (int nt = 0; nt < 2; ++nt)
      #pragma unroll
      for (int r = 0; r < 4; ++r) {
        int qq = mt * 16 + quad * 4 + r;
        int km = nt * 16 + lr;
        int d = km - qq; if (d < 0) d = -d;
        if (d <= 8) maskbits |= 1u << (mt * 8 + nt * 4 + r);
      }

  floatx4 O[2][4] = {};
  float psum[2][4] = {};

  const int kh0 = (qh > 8) ? qh - 8 : 0;
  const int kh1 = (qh < 23) ? qh + 8 : 31;
  const int cnt = kh1 - kh0 + 1;              // 9..17 -> both halves nonempty
  const int cA = (cnt + 1) >> 1;
  const int khA = half ? kh0 + cA : kh0;
  const int khB = half ? kh1 : kh0 + cA - 1;

  const bf16* kpbase = Kpk + (size_t)((b * 2 + s) * 4 + kvh) * 32 * 2048;
  const bf16* vpbase = (s ? Vpk2 : Vpk1) + (size_t)(b * 4 + kvh) * 32 * 2048;

  Frag fA, fB;
  attn_load(fA, kpbase, vpbase, khA, lane8);
  attn_load(fB, kpbase, vpbase, (khA + 1 <= khB) ? khA + 1 : khB, lane8);

  int i = khA;
  while (true) {
    attn_step(qf, fA, maskbits, O, psum, Pl, quad, lr);
    if (i == khB) break;
    ++i;
    attn_load(fA, kpbase, vpbase, (i + 1 <= khB) ? i + 1 : i, lane8);
    attn_step(qf, fB, maskbits, O, psum, Pl, quad, lr);
    if (i == khB) break;
    ++i;
    attn_load(fB, kpbase, vpbase, (i + 1 <= khB) ? i + 1 : i, lane8);
  }

  // ---- combine the two kh-halves per stream (linear: no softmax rescale) ----
  __syncthreads();
  if (half == 1) {
    #pragma unroll
    for (int mt = 0; mt < 2; ++mt)
      #pragma unroll
      for (int ntd = 0; ntd < 4; ++ntd)
        *reinterpret_cast<floatx4*>(&Oslab[(mt * 4 + ntd) * 256 + lane * 4]) = O[mt][ntd];
    floatx4 p0, p1;
    p0[0] = psum[0][0]; p0[1] = psum[0][1]; p0[2] = psum[0][2]; p0[3] = psum[0][3];
    p1[0] = psum[1][0]; p1[1] = psum[1][1]; p1[2] = psum[1][2]; p1[3] = psum[1][3];
    *reinterpret_cast<floatx4*>(&Pslab[lane * 4])       = p0;
    *reinterpret_cast<floatx4*>(&Pslab[256 + lane * 4]) = p1;
  }
  __syncthreads();
  if (half == 0) {
    #pragma unroll
    for (int mt = 0; mt < 2; ++mt)
      #pragma unroll
      for (int ntd = 0; ntd < 4; ++ntd)
        O[mt][ntd] += *reinterpret_cast<const floatx4*>(&Oslab[(mt * 4 + ntd) * 256 + lane * 4]);
    floatx4 p0 = *reinterpret_cast<const floatx4*>(&Pslab[lane * 4]);
    floatx4 p1 = *reinterpret_cast<const floatx4*>(&Pslab[256 + lane * 4]);
    #pragma unroll
    for (int r = 0; r < 4; ++r) { psum[0][r] += p0[r]; psum[1][r] += p1[r]; }

    #pragma unroll
    for (int off = 1; off < 16; off <<= 1)
      #pragma unroll
      for (int mt = 0; mt < 2; ++mt)
        #pragma unroll
        for (int r = 0; r < 4; ++r)
          psum[mt][r] += __shfl_xor(psum[mt][r], off);
    #pragma unroll
    for (int mt = 0; mt < 2; ++mt)
      #pragma unroll
      for (int r = 0; r < 4; ++r)
        psum[mt][r] = 1.f / psum[mt][r];
    #pragma unroll
    for (int mt = 0; mt < 2; ++mt)
      #pragma unroll
      for (int ntd = 0; ntd < 4; ++ntd)
        #pragma unroll
        for (int r = 0; r < 4; ++r)
          O[mt][ntd][r] *= psum[mt][r];

    if (s == 1) {   // publish normalized O2
      #pragma unroll
      for (int mt = 0; mt < 2; ++mt)
        #pragma unroll
        for (int ntd = 0; ntd < 4; ++ntd)
          *reinterpret_cast<floatx4*>(&Oslab[(mt * 4 + ntd) * 256 + lane * 4]) = O[mt][ntd];
    }
  }
  __syncthreads();
  if (w == 0) {     // s=0, half=0: differential combine
    float lam = log1pf(__expf(lambda_p[h]));
    const float* O2slab = (const float*)(smem + 8192);
    #pragma unroll
    for (int mt = 0; mt < 2; ++mt)
      #pragma unroll
      for (int ntd = 0; ntd < 4; ++ntd) {
        floatx4 o2 = *reinterpret_cast<const floatx4*>(&O2slab[(mt * 4 + ntd) * 256 + lane * 4]);
        #pragma unroll
        for (int r = 0; r < 4; ++r) {
          float xv = O[mt][ntd][r] - lam * o2[r];
          *(unsigned short*)&Xs[(mt * 16 + quad * 4 + r) * 72 + ntd * 16 + lr] = f2b(xv);
        }
      }
  }
  __syncthreads();

  // coalesced store of the 32x64 bf16 tile (256 thr = 32 rows x 8 segs)
  {
    int row = t >> 3, seg = t & 7;
    short8 xv = *reinterpret_cast<const short8*>(&Xs[row * 72 + seg * 8]);
    *reinterpret_cast<short8*>(X + (size_t)(tok0 + row) * 768 + h * 64 + seg * 8) = xv;
  }
}

// ---------------------------------------------------------------------------
extern "C" void kernel_launch(void* const* d_in, const int* in_sizes, int n_in,
                              void* d_out, int out_size, void* d_ws, size_t ws_size,
                              hipStream_t stream)
{
  const float* x        = (const float*)d_in[0];
  const float* Wq       = (const float*)d_in[1];
  const float* Wk       = (const float*)d_in[2];
  const float* Wv1      = (const float*)d_in[3];
  const float* Wv2      = (const float*)d_in[4];
  const float* lambda_p = (const float*)d_in[5];
  const float* Wo       = (const float*)d_in[6];
  const float* bo       = (const float*)d_in[7];
  float* out = (float*)d_out;

  bf16* xb   = (bf16*)d_ws;                      // 4096*768
  bf16* Wqb  = xb   + (size_t)NTOK * 768;        // 1536*768
  bf16* Wkb  = Wqb  + (size_t)1536 * 768;        // 512*768
  bf16* Wv1b = Wkb  + (size_t)512 * 768;         // 256*768
  bf16* Wv2b = Wv1b + (size_t)256 * 768;         // 256*768
  bf16* Wob  = Wv2b + (size_t)256 * 768;         // 768*768
  bf16* qb   = Wob  + (size_t)768 * 768;         // 4096*1536
  bf16* kb   = qb   + (size_t)NTOK * 1536;       // 4096*512
  bf16* v1b  = kb   + (size_t)NTOK * 512;        // 4096*256
  bf16* v2b  = v1b  + (size_t)NTOK * 256;        // 4096*256
  bf16* Xb   = v2b  + (size_t)NTOK * 256;        // 4096*768
  bf16* Vpk1 = Xb   + (size_t)NTOK * 768;        // 512 tiles * 2048
  bf16* Vpk2 = Vpk1 + (size_t)512 * 2048;        // 512 tiles * 2048
  bf16* Kpk  = Vpk2 + (size_t)512 * 2048;        // 1024 tiles * 2048

  cvt_all<<<5568, 256, 0, stream>>>(x, Wq, Wk, Wv1, Wv2, Wo,
                                    xb, Wqb, Wkb, Wv1b, Wv2b, Wob);

  gemm_qkv<<<dim3(20, 32), 256, 0, stream>>>(xb, Wqb, Wkb, Wv1b, Wv2b,
                                             qb, kb, v1b, v2b);

  repack_kv<<<2048, 256, 0, stream>>>(kb, v1b, v2b, Kpk, Vpk1, Vpk2);

  attn_mfma<<<BATCH * NH * 32, 256, 0, stream>>>(qb, Kpk, Vpk1, Vpk2, lambda_p, Xb);

  gemm_out<<<dim3(6, 32), 256, 0, stream>>>(Xb, Wob, out, bo);
}